// Round 5
// baseline (23848.366 us; speedup 1.0000x reference)
//
#include <hip/hip_runtime.h>
#include <math.h>

#define NB  8
#define NPX 16384   // 128*128
#define PPX 1024    // 32*32

// f32 LAPACK machine constants (SLAMCH) used for branch tolerances
#define EPS32   5.9604644775390625e-8   // 2^-24 (slamch 'E')
#define EPS232  (EPS32*EPS32)
#define SAFMIN32 1.1754943508222875e-38

// ---------------- workspace layout (bytes), phase-aliased ----------------
static constexpr size_t OFF_VT   = 0;                    // f32 [8][256][256] 2MB (lives across phases)
static constexpr size_t U        = 0x200000;
static constexpr size_t OFF_GRAM = U;                    // f64 [8][256][256] 4MB
static constexpr size_t OFF_A    = U + 0x400000;         // f64 [8][256][256] 4MB reflectors
static constexpr size_t OFF_QB   = U + 0x800000;         // f64 [8][256][256] 4MB Q big (tridiag eigvecs)
static constexpr size_t OFF_SG   = U + 0xC00000;         // f64 [8][256][256] 4MB S scratch
static constexpr size_t OFF_QN   = U + 0x1000000;        // f64 [8][256][256] 4MB Qnew scratch
static constexpr size_t OFF_D    = U + 0x1400000;        // f64 [8][256]
static constexpr size_t OFF_E    = U + 0x1404000;        // f64 [8][256]
static constexpr size_t OFF_TAU  = U + 0x1408000;        // f64 [8][256]
static constexpr size_t OFF_DW   = U + 0x140C000;        // f64 [8][256] working eigenvalues
// phase2 aliases (phase1 dead after k_vt/k_check):
static constexpr size_t OFF_XP   = U;                    // f32 [8][256][1024] 8MB
static constexpr size_t OFF_QKV  = U + 0x800000;         // f32 [8][672][1024] 21MB
static constexpr size_t OFF_POOL = U + 0x1D00000;        // f32 [8][224][1024] 7MB
static constexpr size_t OFF_OWT  = U + 0x2400000;        // f32 [224][256]
// survivors:
static constexpr size_t OFF_LAM  = U + 0x2500000;        // f64 [8][256]
static constexpr size_t OFF_DIAG = U + 0x2504000;        // f32 [4]

// ================= gram = X X^T (f64 accumulate) =================
__global__ __launch_bounds__(256) void k_gram(const float* __restrict__ x, double* __restrict__ gram) {
  int jt = blockIdx.x, it = blockIdx.y, b = blockIdx.z;
  __shared__ float xi[32][129], xj[32][129];
  const float* xb = x + (size_t)b*256*NPX;
  int t = threadIdx.x;
  int ci = t & 31, cjg = t >> 5;
  double acc[4] = {0.0,0.0,0.0,0.0};
  for (int n0 = 0; n0 < NPX; n0 += 128) {
    for (int q = 0; q < 16; ++q) {
      int idx = t + q*256;
      int r = idx >> 7, cc = idx & 127;
      xi[r][cc] = xb[(size_t)(it*32 + r)*NPX + n0 + cc];
      xj[r][cc] = xb[(size_t)(jt*32 + r)*NPX + n0 + cc];
    }
    __syncthreads();
    for (int p = 0; p < 128; ++p) {
      double a = (double)xi[ci][p];
      #pragma unroll
      for (int k = 0; k < 4; ++k) acc[k] += a * (double)xj[cjg + 8*k][p];
    }
    __syncthreads();
  }
  #pragma unroll
  for (int k = 0; k < 4; ++k)
    gram[((size_t)b*256 + it*32 + ci)*256 + jt*32 + cjg + 8*k] = acc[k];
}

__device__ __forceinline__ double blkSum(double v, double* tmp, int t) {
  #pragma unroll
  for (int m = 1; m <= 32; m <<= 1) v += __shfl_xor(v, m);
  __syncthreads();
  if ((t & 63) == 0) tmp[t >> 6] = v;
  __syncthreads();
  return tmp[0] + tmp[1] + tmp[2] + tmp[3];
}

// ================= Householder tridiagonalization (dsytd2 'L', f64) =================
__global__ __launch_bounds__(256) void k_tridiag(const double* __restrict__ gram, double* __restrict__ A,
        double* __restrict__ d_g, double* __restrict__ e_g, double* __restrict__ tau_g) {
  int b = blockIdx.x, t = threadIdx.x;
  const double* gb = gram + (size_t)b*65536;
  double* Ab = A + (size_t)b*65536;
  __shared__ double vL[256], wL[256];
  __shared__ double tmp[4];
  for (int q = 0; q < 256; ++q) Ab[q*256 + t] = gb[q*256 + t];
  __syncthreads();
  for (int i = 0; i < 255; ++i) {
    double part = 0.0;
    int rx = i + 2 + t;
    if (rx < 256) { double v = Ab[i*256 + rx]; part = v*v; }
    double xn2 = blkSum(part, tmp, t);
    double alpha = Ab[i*256 + i + 1];
    double beta, tauv, scale;
    if (xn2 == 0.0) { beta = alpha; tauv = 0.0; scale = 0.0; }
    else {
      beta  = -copysign(sqrt(alpha*alpha + xn2), alpha);   // dlarfg
      tauv  = (beta - alpha)/beta;
      scale = 1.0/(alpha - beta);
    }
    if (t == 0) { e_g[b*256 + i] = beta; tau_g[b*256 + i] = tauv; vL[i+1] = 1.0; }
    if (rx < 256) {
      double v = Ab[i*256 + rx] * scale;
      vL[rx] = v;
      Ab[i*256 + rx] = v;                 // store v in row i for back-transform
    }
    __syncthreads();
    if (tauv != 0.0) {
      int c = i + 1 + t;
      double w = 0.0;
      if (c < 256) {
        for (int r = i + 1; r < 256; ++r) w += Ab[r*256 + c] * vL[r];
        w *= tauv;
        wL[c] = w;
      }
      double part2 = (c < 256) ? vL[c]*w : 0.0;
      double dot = blkSum(part2, tmp, t);
      double coef = -0.5*tauv*dot;
      if (c < 256) wL[c] = w + coef*vL[c];
      __syncthreads();
      if (c < 256) {
        double vc = vL[c], wc = wL[c];
        for (int r = i + 1; r < 256; ++r)
          Ab[r*256 + c] = Ab[r*256 + c] - vL[r]*wc - wL[r]*vc;
      }
      __syncthreads();
    } else {
      __syncthreads();
    }
  }
  d_g[b*256 + t] = Ab[t*256 + t];
  if (t == 0) e_g[b*256 + 255] = 0.0;
}

// ================= LAPACK helpers (device, faithful conventions) =================
__device__ __forceinline__ void dlartg_(double f, double g, double& c, double& s, double& r) {
  // LAPACK >=3.10 convention: c >= 0, r = sign(f)*hypot
  if (g == 0.0) { c = 1.0; s = 0.0; r = f; }
  else if (f == 0.0) { c = 0.0; s = (g > 0.0) ? 1.0 : -1.0; r = fabs(g); }
  else {
    double d = sqrt(f*f + g*g);
    r = (f >= 0.0) ? d : -d;
    c = f / r;
    s = g / r;
  }
}

__device__ void dlaev2_(double a, double b, double cc, double& rt1, double& rt2, double& cs1, double& sn1) {
  double sm = a + cc, df = a - cc;
  double adf = fabs(df), tb = b + b, ab = fabs(tb);
  double acmx, acmn;
  if (fabs(a) > fabs(cc)) { acmx = a; acmn = cc; } else { acmx = cc; acmn = a; }
  double rt;
  if (adf > ab)      rt = adf*sqrt(1.0 + (ab/adf)*(ab/adf));
  else if (adf < ab) rt = ab*sqrt(1.0 + (adf/ab)*(adf/ab));
  else               rt = ab*sqrt(2.0);
  int sgn1;
  if (sm < 0.0)      { rt1 = 0.5*(sm - rt); sgn1 = -1; rt2 = (acmx/rt1)*acmn - (b/rt1)*b; }
  else if (sm > 0.0) { rt1 = 0.5*(sm + rt); sgn1 = 1;  rt2 = (acmx/rt1)*acmn - (b/rt1)*b; }
  else               { rt1 = 0.5*rt; rt2 = -0.5*rt; sgn1 = 1; }
  double cs; int sgn2;
  if (df >= 0.0) { cs = df + rt; sgn2 = 1; } else { cs = df - rt; sgn2 = -1; }
  double acs = fabs(cs);
  if (acs > ab) {
    double ct = -tb/cs;
    sn1 = 1.0/sqrt(1.0 + ct*ct);
    cs1 = ct*sn1;
  } else {
    if (ab == 0.0) { cs1 = 1.0; sn1 = 0.0; }
    else {
      double tn = -cs/tb;
      cs1 = 1.0/sqrt(1.0 + tn*tn);
      sn1 = tn*cs1;
    }
  }
  if (sgn1 == sgn2) { double tn = cs1; cs1 = -sn1; sn1 = tn; }
}

// faithful dsteqr('I') on an n<=16 block, f64 arithmetic with f32 tolerances
__device__ void steqr_leaf(int n, double* d, double* e, double* q, int ldq) {
  // q preinitialized to I by caller
  const double eps = EPS32, eps2 = EPS232, safmin = SAFMIN32;
  int nmaxit = n*30, jtot = 0;
  int l1 = 0;
  while (l1 < n) {
    if (l1 > 0) e[l1-1] = 0.0;
    int m;
    for (m = l1; m < n-1; ++m) {
      double tst = fabs(e[m]);
      if (tst == 0.0) break;
      if (tst <= (sqrt(fabs(d[m]))*sqrt(fabs(d[m+1])))*eps) { e[m] = 0.0; break; }
    }
    int l = l1, lend = m;
    l1 = m + 1;
    if (lend == l) continue;
    if (fabs(d[lend]) < fabs(d[l])) { int tsw = l; l = lend; lend = tsw; }
    if (lend > l) {
      // QL
      while (true) {
        int mm;
        for (mm = l; mm < lend; ++mm) {
          double tst = e[mm]*e[mm];
          if (tst <= (eps2*fabs(d[mm]))*fabs(d[mm+1]) + safmin) break;
        }
        if (mm < lend) e[mm] = 0.0;
        double p = d[l];
        if (mm == l) { l = l + 1; if (l > lend) break; continue; }
        if (mm == l+1) {
          double rt1, rt2, c, s;
          dlaev2_(d[l], e[l], d[l+1], rt1, rt2, c, s);
          for (int i = 0; i < n; ++i) {
            double t1 = q[i*ldq + l+1], t0 = q[i*ldq + l];
            q[i*ldq + l+1] = c*t1 - s*t0;
            q[i*ldq + l]   = s*t1 + c*t0;
          }
          d[l] = rt1; d[l+1] = rt2; e[l] = 0.0;
          l += 2; if (l > lend) break; continue;
        }
        if (jtot == nmaxit) break;
        jtot++;
        double g = (d[l+1] - p)/(2.0*e[l]);
        double r = sqrt(g*g + 1.0);
        g = d[mm] - p + e[l]/(g + copysign(r, g));
        double s = 1.0, c = 1.0; p = 0.0;
        double csv[16], snv[16];
        for (int i = mm-1; i >= l; --i) {
          double f = s*e[i], bb = c*e[i];
          dlartg_(g, f, c, s, r);
          if (i != mm-1) e[i+1] = r;
          g = d[i+1] - p;
          r = (d[i] - g)*s + 2.0*c*bb;
          p = s*r;
          d[i+1] = g + p;
          g = c*r - bb;
          csv[i] = c; snv[i] = -s;
        }
        for (int i = mm-1; i >= l; --i) {       // dlasr 'B'
          double cc2 = csv[i], ss2 = snv[i];
          for (int k = 0; k < n; ++k) {
            double t1 = q[k*ldq + i+1], t0 = q[k*ldq + i];
            q[k*ldq + i+1] = cc2*t1 - ss2*t0;
            q[k*ldq + i]   = ss2*t1 + cc2*t0;
          }
        }
        d[l] -= p; e[l] = g;
      }
    } else {
      // QR
      while (true) {
        int mm;
        for (mm = l; mm > lend; --mm) {
          double tst = e[mm-1]*e[mm-1];
          if (tst <= (eps2*fabs(d[mm]))*fabs(d[mm-1]) + safmin) break;
        }
        if (mm > lend) e[mm-1] = 0.0;
        double p = d[l];
        if (mm == l) { l = l - 1; if (l < lend) break; continue; }
        if (mm == l-1) {
          double rt1, rt2, c, s;
          dlaev2_(d[l-1], e[l-1], d[l], rt1, rt2, c, s);
          for (int i = 0; i < n; ++i) {
            double t1 = q[i*ldq + l], t0 = q[i*ldq + l-1];
            q[i*ldq + l]   = c*t1 - s*t0;
            q[i*ldq + l-1] = s*t1 + c*t0;
          }
          d[l-1] = rt1; d[l] = rt2; e[l-1] = 0.0;
          l -= 2; if (l < lend) break; continue;
        }
        if (jtot == nmaxit) break;
        jtot++;
        double g = (d[l-1] - p)/(2.0*e[l-1]);
        double r = sqrt(g*g + 1.0);
        g = d[mm] - p + e[l-1]/(g + copysign(r, g));
        double s = 1.0, c = 1.0; p = 0.0;
        double csv[16], snv[16];
        for (int i = mm; i <= l-1; ++i) {
          double f = s*e[i], bb = c*e[i];
          dlartg_(g, f, c, s, r);
          if (i != mm) e[i-1] = r;
          g = d[i] - p;
          r = (d[i+1] - g)*s + 2.0*c*bb;
          p = s*r;
          d[i] = g + p;
          g = c*r - bb;
          csv[i] = c; snv[i] = s;
        }
        for (int i = mm; i <= l-1; ++i) {       // dlasr 'F'
          double cc2 = csv[i], ss2 = snv[i];
          for (int k = 0; k < n; ++k) {
            double t1 = q[k*ldq + i+1], t0 = q[k*ldq + i];
            q[k*ldq + i+1] = cc2*t1 - ss2*t0;
            q[k*ldq + i]   = ss2*t1 + cc2*t0;
          }
        }
        d[l] -= p; e[l-1] = g;
      }
    }
  }
  // dsteqr 'I' final: selection sort ascending, swap columns
  for (int ii = 1; ii < n; ++ii) {
    int k = ii - 1; double p = d[k];
    for (int j = ii; j < n; ++j) if (d[j] < p) { k = j; p = d[j]; }
    if (k != ii-1) {
      d[k] = d[ii-1]; d[ii-1] = p;
      for (int r = 0; r < n; ++r) { double tq = q[r*ldq + ii-1]; q[r*ldq + ii-1] = q[r*ldq + k]; q[r*ldq + k] = tq; }
    }
  }
}

__global__ __launch_bounds__(256) void k_zeroq(double* __restrict__ QB) {
  size_t i = (size_t)blockIdx.x*256 + threadIdx.x;
  size_t total = (size_t)NB*65536;
  for (; i < total; i += (size_t)gridDim.x*256) QB[i] = 0.0;
}

// ================= leaves: tears + 16x ssteqr(16) =================
__global__ __launch_bounds__(64) void k_leaves(const double* __restrict__ d_g, const double* __restrict__ e_g,
        double* __restrict__ QB, double* __restrict__ DW) {
  int b = blockIdx.x, t = threadIdx.x;
  __shared__ double dL[256], eL[256];
  __shared__ double ql[16*272];   // 16 leaves x [16][17]
  for (int i = t; i < 256; i += 64) { dL[i] = d_g[b*256 + i]; eL[i] = e_g[b*256 + i]; }
  __syncthreads();
  if (t == 0) {
    for (int cut = 16; cut < 256; cut += 16) {   // dlaed0: tears at all cuts
      double a = fabs(eL[cut-1]);
      dL[cut-1] -= a; dL[cut] -= a;
    }
  }
  __syncthreads();
  if (t < 16) {
    double* q = &ql[t*272];
    for (int i = 0; i < 16; ++i)
      for (int j = 0; j < 16; ++j) q[i*17 + j] = (i == j) ? 1.0 : 0.0;
    steqr_leaf(16, dL + 16*t, eL + 16*t, q, 17);
  }
  __syncthreads();
  for (int idx = t; idx < 4096; idx += 64) {
    int lf = idx >> 8, i = (idx >> 4) & 15, j = idx & 15;
    QB[(size_t)b*65536 + (lf*16 + i)*256 + lf*16 + j] = ql[lf*272 + i*17 + j];
  }
  for (int i = t; i < 256; i += 64) DW[b*256 + i] = dL[i];
}

// ================= one D&C merge level (dlaed1/2/3, faithful deflation) =================
__global__ __launch_bounds__(256) void k_merge(int n1, const double* __restrict__ e_g,
        double* __restrict__ QB, double* __restrict__ DW,
        double* __restrict__ SG, double* __restrict__ QN) {
  int mrg = blockIdx.x, b = blockIdx.y, t = threadIdx.x;
  int nn = 2*n1, r0 = mrg*nn;
  double* Q = QB + (size_t)b*65536;
  double* Sg = SG + (size_t)b*65536;
  double* Qn = QN + (size_t)b*65536;
  __shared__ double dloc[256], zloc[256], dlam[256], wv[256], w2[256], tauv[256], zh[256], dfin[256];
  __shared__ int indx[256], indxp[256], permf[256];
  __shared__ int KK[2];
  __shared__ double sc[3];
  double rho_raw = e_g[b*256 + r0 + n1 - 1];
  if (t < nn) {
    dloc[t] = DW[b*256 + r0 + t];
    double zv = (t < n1) ? Q[(size_t)(r0 + n1 - 1)*256 + r0 + t]
                         : Q[(size_t)(r0 + n1)*256 + r0 + t];
    if (t >= n1 && rho_raw < 0.0) zv = -zv;      // dlaed2
    zloc[t] = zv * 0.70710678118654752440;
  }
  __syncthreads();
  if (t == 0) {
    // dlamrg: merge two ascending runs (ties -> first half)
    int i = 0, jj = n1, pos = 0;
    while (i < n1 && jj < nn) {
      if (dloc[i] <= dloc[jj]) indx[pos++] = i++;
      else indx[pos++] = jj++;
    }
    while (i < n1) indx[pos++] = i++;
    while (jj < nn) indx[pos++] = jj++;
    double maxd = 0.0, maxz = 0.0;
    for (int q2 = 0; q2 < nn; ++q2) {
      maxd = fmax(maxd, fabs(dloc[q2]));
      maxz = fmax(maxz, fabs(zloc[q2]));
    }
    double rho = fabs(2.0*rho_raw);
    double tol = 8.0*EPS32*fmax(maxd, maxz);
    // ----- slaed2 deflation scan -----
    int K = 0, K2 = nn;
    int pj = -1;
    int j = 0;
    for (; j < nn; ++j) {
      int nj = indx[j];
      if (rho*fabs(zloc[nj]) <= tol) { K2--; indxp[K2] = nj; }
      else { pj = nj; break; }
    }
    if (pj >= 0) {
      for (++j; j < nn; ++j) {
        int nj = indx[j];
        if (rho*fabs(zloc[nj]) <= tol) { K2--; indxp[K2] = nj; }
        else {
          double s = zloc[pj], c = zloc[nj];
          double tau = sqrt(c*c + s*s);
          double tdf = dloc[nj] - dloc[pj];
          c /= tau; s = -s/tau;
          if (fabs(tdf*c*s) <= tol) {
            // pair deflation: rotate columns pj,nj, deflate pj
            zloc[nj] = tau; zloc[pj] = 0.0;
            for (int r = 0; r < nn; ++r) {
              double xq = Q[(size_t)(r0 + r)*256 + r0 + pj];
              double yq = Q[(size_t)(r0 + r)*256 + r0 + nj];
              Q[(size_t)(r0 + r)*256 + r0 + pj] = c*xq + s*yq;
              Q[(size_t)(r0 + r)*256 + r0 + nj] = c*yq - s*xq;
            }
            double tt2 = dloc[pj]*c*c + dloc[nj]*s*s;
            dloc[nj] = dloc[pj]*s*s + dloc[nj]*c*c;
            dloc[pj] = tt2;
            K2--;
            int ii2 = 1;
            while (K2 + ii2 <= nn-1 && dloc[pj] < dloc[indxp[K2+ii2]]) {
              indxp[K2+ii2-1] = indxp[K2+ii2]; ii2++;
            }
            indxp[K2+ii2-1] = pj;
            pj = nj;
          } else {
            dlam[K] = dloc[pj]; wv[K] = zloc[pj]; indxp[K] = pj; K++;
            pj = nj;
          }
        }
      }
      dlam[K] = dloc[pj]; wv[K] = zloc[pj]; indxp[K] = pj; K++;
    }
    double sumw2 = 0.0;
    for (int q2 = 0; q2 < K; ++q2) sumw2 += wv[q2]*wv[q2];
    KK[0] = K; KK[1] = K2; sc[0] = rho; sc[1] = tol; sc[2] = sumw2;
  }
  __syncthreads();
  int K = KK[0], K2 = KK[1];
  double rho = sc[0], sumw2 = sc[2];
  if (t < K) w2[t] = rho*wv[t]*wv[t];
  __syncthreads();
  // ----- secular roots (shifted bisection, f64) -----
  if (t < K) {
    double dj = dlam[t];
    double hi0 = (t < K-1) ? (dlam[t+1] - dj) : rho*sumw2;
    double lo = 0.0, hi = hi0;
    for (int it = 0; it < 90; ++it) {
      double mid = 0.5*(lo + hi);
      double f = 1.0;
      for (int j2 = 0; j2 < K; ++j2) {
        double del = (dlam[j2] - dj) - mid;
        f += w2[j2]/del;
      }
      if (f < 0.0) lo = mid; else hi = mid;
    }
    double tl = 0.5*(lo + hi);
    if (tl <= 0.0) tl = hi0*1e-300;
    tauv[t] = tl;
  }
  __syncthreads();
  // ----- Gu-Eisenstat zhat (dlaed3) -----
  if (t < K) {
    double dt = dlam[t];
    double p = tauv[t];
    for (int i = 0; i < K; ++i) {
      if (i == t) continue;
      double del = dlam[i] - dt;
      p *= (del + tauv[i])/del;
    }
    zh[t] = copysign(sqrt(fabs(p)), wv[t]);
  }
  __syncthreads();
  // ----- S columns (normalized) -----
  if (t < K) {
    double dj = dlam[t], tj = tauv[t];
    double nrm = 0.0;
    for (int i = 0; i < K; ++i) {
      double sij = zh[i]/((dlam[i] - dj) - tj);
      nrm += sij*sij;
    }
    double inv = 1.0/sqrt(nrm);
    for (int i = 0; i < K; ++i)
      Sg[(size_t)(r0 + i)*256 + t] = (zh[i]/((dlam[i] - dj) - tj))*inv;
  }
  __syncthreads();
  // ----- GEMM: Qnew(:,0..K) = Qold(:, indxp[0..K)) * S ; copy deflated -----
  if (t < nn) {
    const double* qrow = Q + (size_t)(r0 + t)*256 + r0;
    for (int jt = 0; jt < K; jt += 8) {
      double acc[8] = {0,0,0,0,0,0,0,0};
      int jm = (K - jt < 8) ? (K - jt) : 8;
      for (int i = 0; i < K; ++i) {
        double qv = qrow[indxp[i]];
        const double* srow = Sg + (size_t)(r0 + i)*256 + jt;
        for (int k = 0; k < jm; ++k) acc[k] += qv*srow[k];
      }
      for (int k = 0; k < jm; ++k) Qn[(size_t)(r0 + t)*256 + jt + k] = acc[k];
    }
    for (int p = K2; p < nn; ++p)
      Qn[(size_t)(r0 + t)*256 + K + (p - K2)] = qrow[indxp[p]];
  }
  __syncthreads();
  // ----- final ordering: dlamrg(K asc, N-K desc-backward) -----
  if (t == 0) {
    int i = 0, p = nn - 1, f = 0;
    while (f < nn) {
      bool takesec;
      if (i < K && p >= K2) takesec = ((dlam[i] + tauv[i]) <= dloc[indxp[p]]);
      else takesec = (i < K);
      if (takesec) { dfin[f] = dlam[i] + tauv[i]; permf[f] = i; i++; }
      else         { dfin[f] = dloc[indxp[p]];    permf[f] = K + (p - K2); p--; }
      f++;
    }
  }
  __syncthreads();
  if (t < nn) {
    for (int f = 0; f < nn; ++f)
      Q[(size_t)(r0 + t)*256 + r0 + f] = Qn[(size_t)(r0 + t)*256 + permf[f]];
  }
  if (t == 0) for (int f = 0; f < nn; ++f) DW[b*256 + r0 + f] = dfin[f];
}

// ================= back-transform in place: Z = H(1)..H(254)*Z =================
__global__ __launch_bounds__(256) void k_backxf(const double* __restrict__ A, const double* __restrict__ tau_g,
        double* __restrict__ Zm) {
  int b = blockIdx.x, t = threadIdx.x;
  const double* Ab = A + (size_t)b*65536;
  double* Z = Zm + (size_t)b*65536;
  __shared__ double vL[256];
  for (int s = 253; s >= 0; --s) {
    double tauv = tau_g[b*256 + s];
    if (t == 0) vL[s+1] = 1.0;
    int r = s + 2 + t;
    if (r < 256) vL[r] = Ab[s*256 + r];
    __syncthreads();
    if (tauv != 0.0) {
      double w = 0.0;
      for (int rr = s + 1; rr < 256; ++rr) w += vL[rr]*Z[rr*256 + t];
      double tw = tauv*w;
      for (int rr = s + 1; rr < 256; ++rr) Z[rr*256 + t] -= tw*vL[rr];
    }
    __syncthreads();
  }
}

__global__ __launch_bounds__(256) void k_copylam(const double* __restrict__ DW, double* __restrict__ lam) {
  lam[blockIdx.x*256 + threadIdx.x] = DW[blockIdx.x*256 + threadIdx.x];
}

__global__ __launch_bounds__(256) void k_vt(const double* __restrict__ QB, float* __restrict__ Vt) {
  int c = blockIdx.x, b = blockIdx.y, t = threadIdx.x;
  Vt[((size_t)b*256 + c)*256 + t] = (float)QB[(size_t)b*65536 + (size_t)t*256 + c];
}

// ================= diagnostics =================
__global__ void k_initdiag(float* diag) {
  if (threadIdx.x < 4 && blockIdx.x == 0) diag[threadIdx.x] = 0.0f;
}

__global__ __launch_bounds__(256) void k_check1(const double* __restrict__ gram, const float* __restrict__ Vt,
        const double* __restrict__ lam, float* __restrict__ diag) {
  int it8 = blockIdx.x, b = blockIdx.y, t = threadIdx.x;
  const double* gb = gram + (size_t)b*65536;
  __shared__ float vsh[256];
  float localmax = 0.0f;
  for (int ii = 0; ii < 32; ++ii) {
    int i = it8*32 + ii;
    vsh[t] = Vt[((size_t)b*256 + i)*256 + t];
    __syncthreads();
    double s = 0.0;
    for (int d = 0; d < 256; ++d) s += gb[(size_t)t*256 + d]*(double)vsh[d];
    float r = fabsf((float)(s - lam[b*256 + i]*(double)vsh[t]));
    localmax = fmaxf(localmax, r);
    __syncthreads();
  }
  atomicMax((int*)diag, __float_as_int(localmax));
}

__global__ __launch_bounds__(256) void k_check2(const float* __restrict__ Vt, float* __restrict__ diag) {
  int jt8 = blockIdx.x, b = blockIdx.y, t = threadIdx.x;
  __shared__ float vsh[256];
  float localmax = 0.0f;
  for (int jj = 0; jj < 32; ++jj) {
    int j = jt8*32 + jj;
    vsh[t] = Vt[((size_t)b*256 + j)*256 + t];
    __syncthreads();
    float s = 0.0f;
    const float* vi = Vt + ((size_t)b*256 + t)*256;
    for (int d = 0; d < 256; ++d) s += vi[d]*vsh[d];
    if (t == j) s -= 1.0f;
    localmax = fmaxf(localmax, fabsf(s));
    __syncthreads();
  }
  atomicMax(((int*)diag) + 1, __float_as_int(localmax));
}

__global__ void k_stamp(const float* __restrict__ diag, const double* __restrict__ lam, float* __restrict__ out) {
  if (threadIdx.x != 0 || blockIdx.x != 0) return;
  float r1 = diag[0], r2 = diag[1];
  float mono = 0.0f;
  for (int b = 0; b < 8; ++b)
    for (int i = 0; i < 255; ++i)
      if (lam[b*256 + i + 1] - lam[b*256 + i] < -1e-6) mono = 1.0f;
  float bad = 0.0f;
  if (r1 > 0.25f)       bad = 1.0e4f*(1.0f + fminf(r1, 999.0f));
  else if (r2 > 1e-3f)  bad = 2.0e8f*(1.0f + fminf(r2, 9.0f));
  else if (mono > 0.0f) bad = 5.0e9f;
  if (bad != 0.0f) out[0] = bad;
}

// ================= x_proj = V x, + x, fused maxpool + noise output =================
__global__ __launch_bounds__(256) void k_xproj(const float* __restrict__ x, const float* __restrict__ Vt,
        float* __restrict__ xp, float* __restrict__ noise_out) {
  int R = blockIdx.x, ct = blockIdx.y, b = blockIdx.z;
  int t = threadIdx.x;
  int cl = t >> 3, l8 = t & 7;
  __shared__ float vsh[32][20];
  __shared__ float xs[16][520];
  const float* xb = x + (size_t)b*256*NPX;
  int s0 = R*512;
  float acc[64];
  #pragma unroll
  for (int p = 0; p < 64; ++p) acc[p] = 0.0f;
  for (int d0 = 0; d0 < 256; d0 += 16) {
    for (int q = t; q < 512; q += 256) {
      int c = q >> 4, dd = q & 15;
      vsh[c][dd] = Vt[((size_t)b*256 + ct*32 + c)*256 + d0 + dd];
    }
    for (int q = t; q < 8192; q += 256) {
      int dd = q >> 9, px = q & 511;
      xs[dd][px] = xb[(size_t)(d0 + dd)*NPX + s0 + px];
    }
    __syncthreads();
    for (int dd = 0; dd < 16; ++dd) {
      float a = vsh[cl][dd];
      const float* xr = &xs[dd][l8];
      #pragma unroll
      for (int p = 0; p < 64; ++p) acc[p] += a*xr[8*p];
    }
    __syncthreads();
  }
  int cg = ct*32 + cl;
  const float* xc = xb + (size_t)cg*NPX + s0;
  float vmax[16];
  #pragma unroll
  for (int j = 0; j < 16; ++j) vmax[j] = -3.0e38f;
  bool isnz = (ct == 0);
  #pragma unroll
  for (int p = 0; p < 64; ++p) {
    int px = l8 + 8*p;
    float val = acc[p] + xc[px];
    vmax[p & 15] = fmaxf(vmax[p & 15], val);
    if (isnz) noise_out[((size_t)b*32 + cl)*NPX + s0 + px] = val;
  }
  #pragma unroll
  for (int j = 0; j < 16; ++j) {
    float v = vmax[j];
    v = fmaxf(v, __shfl_xor(v, 1));
    v = fmaxf(v, __shfl_xor(v, 2));
    vmax[j] = v;
  }
  if ((l8 & 3) == 0) {
    int halfsel = l8 >> 2;
    #pragma unroll
    for (int j = 0; j < 16; ++j)
      xp[((size_t)b*256 + cg)*PPX + R*32 + 2*j + halfsel] = vmax[j];
  }
}

// ================= qkv 1x1 conv (672 needed rows) =================
__global__ __launch_bounds__(256) void k_qkv(const float* __restrict__ xp, const float* __restrict__ wq,
        const float* __restrict__ bq, float* __restrict__ qkvm) {
  int pt = blockIdx.x, ot = blockIdx.y, b = blockIdx.z;
  int t = threadIdx.x;
  int ol = t & 31, pg = t >> 5;
  __shared__ float wsh[32][9];
  __shared__ float xsh[8][260];
  float acc[32];
  #pragma unroll
  for (int j = 0; j < 32; ++j) acc[j] = 0.0f;
  for (int ic0 = 0; ic0 < 256; ic0 += 8) {
    {
      int o = t >> 3, j = t & 7;
      int orow = ot*32 + o;
      int reg = orow/224, rem = orow - reg*224;
      int wrow = 32 + rem + 256*reg;
      wsh[o][j] = wq[(size_t)wrow*256 + ic0 + j];
    }
    for (int q = t; q < 2048; q += 256) {
      int ic = q >> 8, px = q & 255;
      xsh[ic][px] = xp[((size_t)b*256 + ic0 + ic)*PPX + pt*256 + px];
    }
    __syncthreads();
    for (int ic = 0; ic < 8; ++ic) {
      float a = wsh[ol][ic];
      const float* xr = &xsh[ic][pg];
      #pragma unroll
      for (int j = 0; j < 32; ++j) acc[j] += a*xr[8*j];
    }
    __syncthreads();
  }
  int orow = ot*32 + ol;
  int reg = orow/224, rem = orow - reg*224;
  float bv = bq[32 + rem + 256*reg];
  #pragma unroll
  for (int j = 0; j < 32; ++j)
    qkvm[((size_t)b*672 + orow)*PPX + pt*256 + pg + 8*j] = acc[j] + bv;
}

// ================= attention =================
__global__ __launch_bounds__(256) void k_attn(const float* __restrict__ qkvm, const float* __restrict__ emb,
        const float* __restrict__ xp, float* __restrict__ pool) {
  int rt = blockIdx.x, n = blockIdx.y, b = blockIdx.z;
  int t = threadIdx.x;
  int rl = t >> 5, pg = t & 31;
  __shared__ float S[8][1032];
  __shared__ float qsh[8][33];
  __shared__ float kv[4224];
  const float* qb = qkvm + (size_t)b*672*PPX;
  int rg0 = rt*8;
  {
    int rg = rg0 + rl;
    float qv = qb[(size_t)(32*n + (rg >> 5))*PPX + ((rg & 31) << 5) + pg];
    float ev = emb[(((size_t)n*8 + b)*1024 + rg)*32 + pg];
    qsh[rl][pg] = (qv + ev)*0.17677669529663688f;
  }
  __syncthreads();
  const float* kb = qb + (size_t)(224 + 32*n)*PPX;
  for (int p0 = 0; p0 < 1024; p0 += 128) {
    for (int q = t; q < 4096; q += 256) {
      int c = q >> 7, pp = q & 127;
      kv[c*132 + pp] = kb[(size_t)c*PPX + p0 + pp];
    }
    __syncthreads();
    float a0 = 0, a1 = 0, a2 = 0, a3 = 0;
    for (int c = 0; c < 32; ++c) {
      float qv = qsh[rl][c];
      const float* kr = &kv[c*132 + pg];
      a0 += qv*kr[0]; a1 += qv*kr[32]; a2 += qv*kr[64]; a3 += qv*kr[96];
    }
    S[rl][p0 + pg]      = a0;
    S[rl][p0 + pg + 32] = a1;
    S[rl][p0 + pg + 64] = a2;
    S[rl][p0 + pg + 96] = a3;
    __syncthreads();
  }
  float mx = -3.0e38f;
  for (int j = 0; j < 32; ++j) mx = fmaxf(mx, S[rl][pg + 32*j]);
  #pragma unroll
  for (int m = 1; m <= 16; m <<= 1) mx = fmaxf(mx, __shfl_xor(mx, m));
  float sum = 0.0f;
  for (int j = 0; j < 32; ++j) {
    float e = expf(S[rl][pg + 32*j] - mx);
    S[rl][pg + 32*j] = e;
    sum += e;
  }
  #pragma unroll
  for (int m = 1; m <= 16; m <<= 1) sum += __shfl_xor(sum, m);
  float inv = 1.0f/sum;
  for (int j = 0; j < 32; ++j) S[rl][pg + 32*j] *= inv;
  __syncthreads();
  const float* vb = qb + (size_t)(448 + 32*n)*PPX;
  float acc = 0.0f;
  for (int p0 = 0; p0 < 1024; p0 += 128) {
    for (int q = t; q < 4096; q += 256) {
      int pp = q >> 5, c = q & 31;
      int p = p0 + pp;
      kv[pp*33 + c] = vb[(size_t)(p >> 5)*PPX + ((p & 31) << 5) + c];
    }
    __syncthreads();
    for (int pp = 0; pp < 128; ++pp) acc += S[rl][p0 + pp]*kv[pp*33 + pg];
    __syncthreads();
  }
  int rg = rg0 + rl;
  int ch = 32*n + (rg >> 5);
  size_t sp = (size_t)((rg & 31) << 5) + pg;
  pool[((size_t)b*224 + ch)*PPX + sp] = acc + xp[((size_t)b*256 + 32 + ch)*PPX + sp];
}

__global__ void k_owt(const float* __restrict__ ow, float* __restrict__ owt) {
  int t = blockIdx.x*256 + threadIdx.x;
  if (t < 256*224) {
    int oc = t/224, ch = t - oc*224;
    owt[(size_t)ch*256 + oc] = ow[t];
  }
}

// ================= bilinear + sim gating + final conv =================
__global__ __launch_bounds__(256) void k_final(const float* __restrict__ pool, const float* __restrict__ noise,
        const float* __restrict__ sim_w, const float* __restrict__ owt, float* __restrict__ out) {
  int tt = blockIdx.x, b = blockIdx.y;
  int t = threadIdx.x;
  int h = tt >> 3, w0 = (tt & 7)*16;
  __shared__ float xa[224][20];
  __shared__ float nsc[224][20];
  __shared__ float nz[32][20];
  __shared__ float scl[16];
  for (int q = t; q < 512; q += 256) {
    int c = q >> 4, px = q & 15;
    nz[c][px] = noise[((size_t)b*32 + c)*NPX + h*128 + w0 + px];
  }
  float hs = h*0.25f - 0.375f;
  float hf = floorf(hs);
  int h0 = (int)hf;
  float fh = hs - hf;
  int h0c = min(max(h0, 0), 31);
  int h1c = min(max(h0 + 1, 0), 31);
  __syncthreads();
  for (int q = t; q < 3584; q += 256) {
    int c = q >> 4, px = q & 15;
    int w = w0 + px;
    float wsrc = w*0.25f - 0.375f;
    float wf = floorf(wsrc);
    int W0 = (int)wf;
    float fw = wsrc - wf;
    int w0c = min(max(W0, 0), 31);
    int w1c = min(max(W0 + 1, 0), 31);
    const float* pb = pool + ((size_t)b*224 + c)*PPX;
    float v00 = pb[h0c*32 + w0c], v01 = pb[h0c*32 + w1c];
    float v10 = pb[h1c*32 + w0c], v11 = pb[h1c*32 + w1c];
    xa[c][px] = (1.0f - fh)*((1.0f - fw)*v00 + fw*v01) + fh*((1.0f - fw)*v10 + fw*v11);
    float np = 0.0f;
    #pragma unroll
    for (int j = 0; j < 32; ++j) np += sim_w[c*32 + j]*nz[j][px];
    nsc[c][px] = np;
  }
  __syncthreads();
  {
    int px = t >> 4, kk = t & 15;
    float s1 = 0, s2 = 0, s3 = 0;
    for (int c = kk; c < 224; c += 16) {
      float a = xa[c][px], p = nsc[c][px];
      s1 += a*a; s2 += p*p; s3 += a*p;
    }
    #pragma unroll
    for (int m = 1; m <= 8; m <<= 1) {
      s1 += __shfl_xor(s1, m);
      s2 += __shfl_xor(s2, m);
      s3 += __shfl_xor(s3, m);
    }
    if (kk == 0) {
      float n1 = fmaxf(sqrtf(s1), 1e-12f);
      float n2 = fmaxf(sqrtf(s2), 1e-12f);
      float sim = (s3/(n1*n2) + 1.0f)*0.5f;
      scl[px] = 1.0f - sim;
    }
  }
  __syncthreads();
  {
    float accp[16];
    #pragma unroll
    for (int px = 0; px < 16; ++px) accp[px] = 0.0f;
    for (int c = 0; c < 224; ++c) {
      float wv = owt[(size_t)c*256 + t];
      #pragma unroll
      for (int px = 0; px < 16; ++px) accp[px] += wv*xa[c][px];
    }
    size_t obase = ((size_t)b*256 + t)*NPX + (size_t)h*128 + w0;
    #pragma unroll
    for (int px = 0; px < 16; ++px) out[obase + px] = accp[px]*scl[px];
  }
  if (b == 0 && tt == 0 && t == 0) out[(size_t)33554432] = 8.0f;   // AVG_K
}

extern "C" void kernel_launch(void* const* d_in, const int* in_sizes, int n_in,
                              void* d_out, int out_size, void* d_ws, size_t ws_size,
                              hipStream_t stream) {
  (void)in_sizes; (void)n_in; (void)out_size; (void)ws_size;
  const float* x     = (const float*)d_in[0];
  const float* qkv_w = (const float*)d_in[1];
  const float* qkv_b = (const float*)d_in[2];
  const float* emb   = (const float*)d_in[3];
  const float* sim_w = (const float*)d_in[4];
  const float* out_w = (const float*)d_in[5];
  float* out = (float*)d_out;
  char* ws = (char*)d_ws;
  double* gram = (double*)(ws + OFF_GRAM);
  double* A    = (double*)(ws + OFF_A);
  double* QB   = (double*)(ws + OFF_QB);
  double* SG   = (double*)(ws + OFF_SG);
  double* QN   = (double*)(ws + OFF_QN);
  double* d_a  = (double*)(ws + OFF_D);
  double* e_a  = (double*)(ws + OFF_E);
  double* tau_a= (double*)(ws + OFF_TAU);
  double* DW   = (double*)(ws + OFF_DW);
  float*  Vt   = (float*) (ws + OFF_VT);
  float*  xp   = (float*) (ws + OFF_XP);
  float*  qkvm = (float*) (ws + OFF_QKV);
  float*  pool = (float*) (ws + OFF_POOL);
  float*  owt  = (float*) (ws + OFF_OWT);
  double* lam  = (double*)(ws + OFF_LAM);
  float*  diag = (float*) (ws + OFF_DIAG);
  float*  noise_out = out + 33554433;

  k_initdiag<<<dim3(1),      64,  0, stream>>>(diag);
  k_gram   <<<dim3(8,8,8),   256, 0, stream>>>(x, gram);
  k_tridiag<<<dim3(8),       256, 0, stream>>>(gram, A, d_a, e_a, tau_a);
  k_zeroq  <<<dim3(512),     256, 0, stream>>>(QB);
  k_leaves <<<dim3(8),       64,  0, stream>>>(d_a, e_a, QB, DW);
  k_merge  <<<dim3(8,8),     256, 0, stream>>>(16,  e_a, QB, DW, SG, QN);
  k_merge  <<<dim3(4,8),     256, 0, stream>>>(32,  e_a, QB, DW, SG, QN);
  k_merge  <<<dim3(2,8),     256, 0, stream>>>(64,  e_a, QB, DW, SG, QN);
  k_merge  <<<dim3(1,8),     256, 0, stream>>>(128, e_a, QB, DW, SG, QN);
  k_backxf <<<dim3(8),       256, 0, stream>>>(A, tau_a, QB);
  k_copylam<<<dim3(8),       256, 0, stream>>>(DW, lam);
  k_vt     <<<dim3(256,8),   256, 0, stream>>>(QB, Vt);
  k_check1 <<<dim3(8,8),     256, 0, stream>>>(gram, Vt, lam, diag);
  k_check2 <<<dim3(8,8),     256, 0, stream>>>(Vt, diag);
  k_xproj  <<<dim3(32,8,8),  256, 0, stream>>>(x, Vt, xp, noise_out);
  k_qkv    <<<dim3(4,21,8),  256, 0, stream>>>(xp, qkv_w, qkv_b, qkvm);
  k_attn   <<<dim3(128,7,8), 256, 0, stream>>>(qkvm, emb, xp, pool);
  k_owt    <<<dim3(224),     256, 0, stream>>>(out_w, owt);
  k_final  <<<dim3(1024,8),  256, 0, stream>>>(pool, noise_out, sim_w, owt, out);
  k_stamp  <<<dim3(1),       64,  0, stream>>>(diag, lam, out);
}

// Round 6
// 19490.309 us; speedup vs baseline: 1.2236x; 1.2236x over previous
//
#include <hip/hip_runtime.h>
#include <math.h>

#define NB  8
#define NPX 16384   // 128*128
#define PPX 1024    // 32*32

// f32 LAPACK machine constants (SLAMCH) used for branch tolerances
#define EPS32   5.9604644775390625e-8   // 2^-24 (slamch 'E')
#define EPS232  (EPS32*EPS32)
#define SAFMIN32 1.1754943508222875e-38

// ---------------- workspace layout (bytes), phase-aliased ----------------
static constexpr size_t OFF_VT   = 0;                    // f32 [8][256][256] 2MB (lives across phases)
static constexpr size_t U        = 0x200000;
static constexpr size_t OFF_GRAM = U;                    // f64 [8][256][256] 4MB
static constexpr size_t OFF_A    = U + 0x400000;         // f64 [8][256][256] 4MB reflectors
static constexpr size_t OFF_QT   = U + 0x800000;         // f64 [8][256][256] 4MB QT[col][row] (tridiag eigvecs, transposed)
static constexpr size_t OFF_SG   = U + 0xC00000;         // f64 [8][256][256] 4MB S scratch
static constexpr size_t OFF_QN   = U + 0x1000000;        // f64 [8][256][256] 4MB QNT scratch
static constexpr size_t OFF_D    = U + 0x1400000;        // f64 [8][256]
static constexpr size_t OFF_E    = U + 0x1404000;        // f64 [8][256]
static constexpr size_t OFF_TAU  = U + 0x1408000;        // f64 [8][256]
static constexpr size_t OFF_DW   = U + 0x140C000;        // f64 [8][256] working eigenvalues
static constexpr size_t OFF_META = U + 0x1410000;        // int [8][8][520]  K,K2,indxp[256],permf[256]
// phase2 aliases (phase1 dead in order: GRAM after tridiag, A after backxf, QT after vt, SG/QN/META after merges):
static constexpr size_t OFF_XP   = U;                    // f32 [8][256][1024] 8MB
static constexpr size_t OFF_QKV  = U + 0x800000;         // f32 [8][672][1024] 21MB
static constexpr size_t OFF_POOL = U + 0x1D00000;        // f32 [8][224][1024] 7MB
static constexpr size_t OFF_OWT  = U + 0x2400000;        // f32 [224][256]

// ================= gram = X X^T (f64 accumulate) =================
__global__ __launch_bounds__(256) void k_gram(const float* __restrict__ x, double* __restrict__ gram) {
  int jt = blockIdx.x, it = blockIdx.y, b = blockIdx.z;
  __shared__ float xi[32][129], xj[32][129];
  const float* xb = x + (size_t)b*256*NPX;
  int t = threadIdx.x;
  int ci = t & 31, cjg = t >> 5;
  double acc[4] = {0.0,0.0,0.0,0.0};
  for (int n0 = 0; n0 < NPX; n0 += 128) {
    for (int q = 0; q < 16; ++q) {
      int idx = t + q*256;
      int r = idx >> 7, cc = idx & 127;
      xi[r][cc] = xb[(size_t)(it*32 + r)*NPX + n0 + cc];
      xj[r][cc] = xb[(size_t)(jt*32 + r)*NPX + n0 + cc];
    }
    __syncthreads();
    for (int p = 0; p < 128; ++p) {
      double a = (double)xi[ci][p];
      #pragma unroll
      for (int k = 0; k < 4; ++k) acc[k] += a * (double)xj[cjg + 8*k][p];
    }
    __syncthreads();
  }
  #pragma unroll
  for (int k = 0; k < 4; ++k)
    gram[((size_t)b*256 + it*32 + ci)*256 + jt*32 + cjg + 8*k] = acc[k];
}

__device__ __forceinline__ double blkSum(double v, double* tmp, int t) {
  #pragma unroll
  for (int m = 1; m <= 32; m <<= 1) v += __shfl_xor(v, m);
  __syncthreads();
  if ((t & 63) == 0) tmp[t >> 6] = v;
  __syncthreads();
  return tmp[0] + tmp[1] + tmp[2] + tmp[3];
}

// ================= Householder tridiagonalization (dsytd2 'L', f64) =================
__global__ __launch_bounds__(256) void k_tridiag(const double* __restrict__ gram, double* __restrict__ A,
        double* __restrict__ d_g, double* __restrict__ e_g, double* __restrict__ tau_g) {
  int b = blockIdx.x, t = threadIdx.x;
  const double* gb = gram + (size_t)b*65536;
  double* Ab = A + (size_t)b*65536;
  __shared__ double vL[256], wL[256];
  __shared__ double tmp[4];
  for (int q = 0; q < 256; ++q) Ab[q*256 + t] = gb[q*256 + t];
  __syncthreads();
  for (int i = 0; i < 255; ++i) {
    double part = 0.0;
    int rx = i + 2 + t;
    if (rx < 256) { double v = Ab[i*256 + rx]; part = v*v; }
    double xn2 = blkSum(part, tmp, t);
    double alpha = Ab[i*256 + i + 1];
    double beta, tauv, scale;
    if (xn2 == 0.0) { beta = alpha; tauv = 0.0; scale = 0.0; }
    else {
      beta  = -copysign(sqrt(alpha*alpha + xn2), alpha);   // dlarfg
      tauv  = (beta - alpha)/beta;
      scale = 1.0/(alpha - beta);
    }
    if (t == 0) { e_g[b*256 + i] = beta; tau_g[b*256 + i] = tauv; vL[i+1] = 1.0; }
    if (rx < 256) {
      double v = Ab[i*256 + rx] * scale;
      vL[rx] = v;
      Ab[i*256 + rx] = v;                 // store v in row i for back-transform
    }
    __syncthreads();
    if (tauv != 0.0) {
      int c = i + 1 + t;
      double w = 0.0;
      if (c < 256) {
        for (int r = i + 1; r < 256; ++r) w += Ab[r*256 + c] * vL[r];
        w *= tauv;
        wL[c] = w;
      }
      double part2 = (c < 256) ? vL[c]*w : 0.0;
      double dot = blkSum(part2, tmp, t);
      double coef = -0.5*tauv*dot;
      if (c < 256) wL[c] = w + coef*vL[c];
      __syncthreads();
      if (c < 256) {
        double vc = vL[c], wc = wL[c];
        for (int r = i + 1; r < 256; ++r)
          Ab[r*256 + c] = Ab[r*256 + c] - vL[r]*wc - wL[r]*vc;
      }
      __syncthreads();
    } else {
      __syncthreads();
    }
  }
  d_g[b*256 + t] = Ab[t*256 + t];
  if (t == 0) e_g[b*256 + 255] = 0.0;
}

// ================= LAPACK helpers =================
__device__ __forceinline__ void dlartg_(double f, double g, double& c, double& s, double& r) {
  if (g == 0.0) { c = 1.0; s = 0.0; r = f; }
  else if (f == 0.0) { c = 0.0; s = (g > 0.0) ? 1.0 : -1.0; r = fabs(g); }
  else {
    double d = sqrt(f*f + g*g);
    r = (f >= 0.0) ? d : -d;
    c = f / r;
    s = g / r;
  }
}

__device__ void dlaev2_(double a, double b, double cc, double& rt1, double& rt2, double& cs1, double& sn1) {
  double sm = a + cc, df = a - cc;
  double adf = fabs(df), tb = b + b, ab = fabs(tb);
  double acmx, acmn;
  if (fabs(a) > fabs(cc)) { acmx = a; acmn = cc; } else { acmx = cc; acmn = a; }
  double rt;
  if (adf > ab)      rt = adf*sqrt(1.0 + (ab/adf)*(ab/adf));
  else if (adf < ab) rt = ab*sqrt(1.0 + (adf/ab)*(adf/ab));
  else               rt = ab*sqrt(2.0);
  int sgn1;
  if (sm < 0.0)      { rt1 = 0.5*(sm - rt); sgn1 = -1; rt2 = (acmx/rt1)*acmn - (b/rt1)*b; }
  else if (sm > 0.0) { rt1 = 0.5*(sm + rt); sgn1 = 1;  rt2 = (acmx/rt1)*acmn - (b/rt1)*b; }
  else               { rt1 = 0.5*rt; rt2 = -0.5*rt; sgn1 = 1; }
  double cs; int sgn2;
  if (df >= 0.0) { cs = df + rt; sgn2 = 1; } else { cs = df - rt; sgn2 = -1; }
  double acs = fabs(cs);
  if (acs > ab) {
    double ct = -tb/cs;
    sn1 = 1.0/sqrt(1.0 + ct*ct);
    cs1 = ct*sn1;
  } else {
    if (ab == 0.0) { cs1 = 1.0; sn1 = 0.0; }
    else {
      double tn = -cs/tb;
      cs1 = 1.0/sqrt(1.0 + tn*tn);
      sn1 = tn*cs1;
    }
  }
  if (sgn1 == sgn2) { double tn = cs1; cs1 = -sn1; sn1 = tn; }
}

// faithful dsteqr('I') on an n<=16 block, f64 arithmetic with f32 tolerances
__device__ void steqr_leaf(int n, double* d, double* e, double* q, int ldq) {
  const double eps = EPS32, eps2 = EPS232, safmin = SAFMIN32;
  int nmaxit = n*30, jtot = 0;
  int l1 = 0;
  while (l1 < n) {
    if (l1 > 0) e[l1-1] = 0.0;
    int m;
    for (m = l1; m < n-1; ++m) {
      double tst = fabs(e[m]);
      if (tst == 0.0) break;
      if (tst <= (sqrt(fabs(d[m]))*sqrt(fabs(d[m+1])))*eps) { e[m] = 0.0; break; }
    }
    int l = l1, lend = m;
    l1 = m + 1;
    if (lend == l) continue;
    if (fabs(d[lend]) < fabs(d[l])) { int tsw = l; l = lend; lend = tsw; }
    if (lend > l) {
      while (true) {
        int mm;
        for (mm = l; mm < lend; ++mm) {
          double tst = e[mm]*e[mm];
          if (tst <= (eps2*fabs(d[mm]))*fabs(d[mm+1]) + safmin) break;
        }
        if (mm < lend) e[mm] = 0.0;
        double p = d[l];
        if (mm == l) { l = l + 1; if (l > lend) break; continue; }
        if (mm == l+1) {
          double rt1, rt2, c, s;
          dlaev2_(d[l], e[l], d[l+1], rt1, rt2, c, s);
          for (int i = 0; i < n; ++i) {
            double t1 = q[i*ldq + l+1], t0 = q[i*ldq + l];
            q[i*ldq + l+1] = c*t1 - s*t0;
            q[i*ldq + l]   = s*t1 + c*t0;
          }
          d[l] = rt1; d[l+1] = rt2; e[l] = 0.0;
          l += 2; if (l > lend) break; continue;
        }
        if (jtot == nmaxit) break;
        jtot++;
        double g = (d[l+1] - p)/(2.0*e[l]);
        double r = sqrt(g*g + 1.0);
        g = d[mm] - p + e[l]/(g + copysign(r, g));
        double s = 1.0, c = 1.0; p = 0.0;
        double csv[16], snv[16];
        for (int i = mm-1; i >= l; --i) {
          double f = s*e[i], bb = c*e[i];
          dlartg_(g, f, c, s, r);
          if (i != mm-1) e[i+1] = r;
          g = d[i+1] - p;
          r = (d[i] - g)*s + 2.0*c*bb;
          p = s*r;
          d[i+1] = g + p;
          g = c*r - bb;
          csv[i] = c; snv[i] = -s;
        }
        for (int i = mm-1; i >= l; --i) {
          double cc2 = csv[i], ss2 = snv[i];
          for (int k = 0; k < n; ++k) {
            double t1 = q[k*ldq + i+1], t0 = q[k*ldq + i];
            q[k*ldq + i+1] = cc2*t1 - ss2*t0;
            q[k*ldq + i]   = ss2*t1 + cc2*t0;
          }
        }
        d[l] -= p; e[l] = g;
      }
    } else {
      while (true) {
        int mm;
        for (mm = l; mm > lend; --mm) {
          double tst = e[mm-1]*e[mm-1];
          if (tst <= (eps2*fabs(d[mm]))*fabs(d[mm-1]) + safmin) break;
        }
        if (mm > lend) e[mm-1] = 0.0;
        double p = d[l];
        if (mm == l) { l = l - 1; if (l < lend) break; continue; }
        if (mm == l-1) {
          double rt1, rt2, c, s;
          dlaev2_(d[l-1], e[l-1], d[l], rt1, rt2, c, s);
          for (int i = 0; i < n; ++i) {
            double t1 = q[i*ldq + l], t0 = q[i*ldq + l-1];
            q[i*ldq + l]   = c*t1 - s*t0;
            q[i*ldq + l-1] = s*t1 + c*t0;
          }
          d[l-1] = rt1; d[l] = rt2; e[l-1] = 0.0;
          l -= 2; if (l < lend) break; continue;
        }
        if (jtot == nmaxit) break;
        jtot++;
        double g = (d[l-1] - p)/(2.0*e[l-1]);
        double r = sqrt(g*g + 1.0);
        g = d[mm] - p + e[l-1]/(g + copysign(r, g));
        double s = 1.0, c = 1.0; p = 0.0;
        double csv[16], snv[16];
        for (int i = mm; i <= l-1; ++i) {
          double f = s*e[i], bb = c*e[i];
          dlartg_(g, f, c, s, r);
          if (i != mm) e[i-1] = r;
          g = d[i] - p;
          r = (d[i+1] - g)*s + 2.0*c*bb;
          p = s*r;
          d[i] = g + p;
          g = c*r - bb;
          csv[i] = c; snv[i] = s;
        }
        for (int i = mm; i <= l-1; ++i) {
          double cc2 = csv[i], ss2 = snv[i];
          for (int k = 0; k < n; ++k) {
            double t1 = q[k*ldq + i+1], t0 = q[k*ldq + i];
            q[k*ldq + i+1] = cc2*t1 - ss2*t0;
            q[k*ldq + i]   = ss2*t1 + cc2*t0;
          }
        }
        d[l] -= p; e[l-1] = g;
      }
    }
  }
  for (int ii = 1; ii < n; ++ii) {
    int k = ii - 1; double p = d[k];
    for (int j = ii; j < n; ++j) if (d[j] < p) { k = j; p = d[j]; }
    if (k != ii-1) {
      d[k] = d[ii-1]; d[ii-1] = p;
      for (int r = 0; r < n; ++r) { double tq = q[r*ldq + ii-1]; q[r*ldq + ii-1] = q[r*ldq + k]; q[r*ldq + k] = tq; }
    }
  }
}

__global__ __launch_bounds__(256) void k_zeroq(double* __restrict__ QT) {
  size_t i = (size_t)blockIdx.x*256 + threadIdx.x;
  size_t total = (size_t)NB*65536;
  for (; i < total; i += (size_t)gridDim.x*256) QT[i] = 0.0;
}

// ================= leaves: tears + 16x ssteqr(16), write TRANSPOSED (QT[eigvec][component]) =================
__global__ __launch_bounds__(64) void k_leaves(const double* __restrict__ d_g, const double* __restrict__ e_g,
        double* __restrict__ QT, double* __restrict__ DW) {
  int b = blockIdx.x, t = threadIdx.x;
  __shared__ double dL[256], eL[256];
  __shared__ double ql[16*272];   // 16 leaves x [16][17]
  for (int i = t; i < 256; i += 64) { dL[i] = d_g[b*256 + i]; eL[i] = e_g[b*256 + i]; }
  __syncthreads();
  if (t == 0) {
    for (int cut = 16; cut < 256; cut += 16) {
      double a = fabs(eL[cut-1]);
      dL[cut-1] -= a; dL[cut] -= a;
    }
  }
  __syncthreads();
  if (t < 16) {
    double* q = &ql[t*272];
    for (int i = 0; i < 16; ++i)
      for (int j = 0; j < 16; ++j) q[i*17 + j] = (i == j) ? 1.0 : 0.0;
    steqr_leaf(16, dL + 16*t, eL + 16*t, q, 17);
  }
  __syncthreads();
  for (int idx = t; idx < 4096; idx += 64) {
    int lf = idx >> 8, i = (idx >> 4) & 15, j = idx & 15;
    // QT[col=eigvec (lf*16+j)][row=component (lf*16+i)] = q[i][j]
    QT[(size_t)b*65536 + (size_t)(lf*16 + j)*256 + lf*16 + i] = ql[lf*272 + i*17 + j];
  }
  for (int i = t; i < 256; i += 64) DW[b*256 + i] = dL[i];
}

// ================= merge phase 1: scan + rotations + secular + S (dlaed1/2/3 faithful) =================
__global__ __launch_bounds__(256) void k_mscan(int n1, const double* __restrict__ e_g,
        double* __restrict__ QT, double* __restrict__ DW, double* __restrict__ SG, int* __restrict__ META) {
  int mrg = blockIdx.x, b = blockIdx.y, t = threadIdx.x;
  int nn = 2*n1, r0 = mrg*nn;
  double* Q = QT + (size_t)b*65536;
  double* Sg = SG + (size_t)b*65536;
  int* meta = META + ((b*8 + mrg)*520);
  __shared__ double dloc[256], zloc[256], dlam[256], wv[256], w2[256], tauv[256], zh[256], dfin[256];
  __shared__ int indx[256], indxp[256], permf[256];
  __shared__ double rotc[256], rots[256];
  __shared__ short rotp[256], rotq[256];
  __shared__ int KK[3];
  __shared__ double sc[2];
  double rho_raw = e_g[b*256 + r0 + n1 - 1];
  if (t < nn) {
    dloc[t] = DW[b*256 + r0 + t];
    // z = [last row of Q1 ; first row of Q2] -> with QT layout: component (n1-1 | n1) of eigvec t
    double zv = Q[(size_t)(r0 + t)*256 + r0 + ((t < n1) ? (n1 - 1) : n1)];
    if (t >= n1 && rho_raw < 0.0) zv = -zv;      // dlaed2
    zloc[t] = zv * 0.70710678118654752440;
  }
  __syncthreads();
  if (t == 0) {
    // dlamrg merge of two ascending runs (ties -> first half)
    int i = 0, jj = n1, pos = 0;
    while (i < n1 && jj < nn) { if (dloc[i] <= dloc[jj]) indx[pos++] = i++; else indx[pos++] = jj++; }
    while (i < n1) indx[pos++] = i++;
    while (jj < nn) indx[pos++] = jj++;
    double maxd = 0.0, maxz = 0.0;
    for (int q2 = 0; q2 < nn; ++q2) { maxd = fmax(maxd, fabs(dloc[q2])); maxz = fmax(maxz, fabs(zloc[q2])); }
    double rho = fabs(2.0*rho_raw);
    double tol = 8.0*EPS32*fmax(maxd, maxz);
    // slaed2 deflation scan (rotations deferred -> recorded)
    int K = 0, K2 = nn, nrot = 0, pj = -1, j = 0;
    for (; j < nn; ++j) {
      int nj = indx[j];
      if (rho*fabs(zloc[nj]) <= tol) { K2--; indxp[K2] = nj; }
      else { pj = nj; break; }
    }
    if (pj >= 0) {
      for (++j; j < nn; ++j) {
        int nj = indx[j];
        if (rho*fabs(zloc[nj]) <= tol) { K2--; indxp[K2] = nj; }
        else {
          double s = zloc[pj], c = zloc[nj];
          double tau = sqrt(c*c + s*s);
          double tdf = dloc[nj] - dloc[pj];
          c /= tau; s = -s/tau;
          if (fabs(tdf*c*s) <= tol) {
            zloc[nj] = tau; zloc[pj] = 0.0;
            rotp[nrot] = (short)pj; rotq[nrot] = (short)nj; rotc[nrot] = c; rots[nrot] = s; nrot++;
            double tt2 = dloc[pj]*c*c + dloc[nj]*s*s;
            dloc[nj] = dloc[pj]*s*s + dloc[nj]*c*c;
            dloc[pj] = tt2;
            K2--;
            int ii2 = 1;
            while (K2 + ii2 <= nn - 1 && dloc[pj] < dloc[indxp[K2 + ii2]]) { indxp[K2+ii2-1] = indxp[K2+ii2]; ii2++; }
            indxp[K2+ii2-1] = pj;
            pj = nj;
          } else {
            dlam[K] = dloc[pj]; wv[K] = zloc[pj]; indxp[K] = pj; K++;
            pj = nj;
          }
        }
      }
      dlam[K] = dloc[pj]; wv[K] = zloc[pj]; indxp[K] = pj; K++;
    }
    double sumw2 = 0.0;
    for (int q2 = 0; q2 < K; ++q2) sumw2 += wv[q2]*wv[q2];
    KK[0] = K; KK[1] = K2; KK[2] = nrot; sc[0] = rho; sc[1] = sumw2;
  }
  __syncthreads();
  int K = KK[0], K2 = KK[1], nrot = KK[2];
  double rho = sc[0], sumw2 = sc[1];
  // apply recorded Givens rotations in order; thread t owns component t of both columns -> no barriers needed
  if (t < nn) {
    for (int k = 0; k < nrot; ++k) {
      int p = rotp[k], q = rotq[k];
      double c = rotc[k], s = rots[k];
      size_t ip = (size_t)(r0 + p)*256 + r0 + t;
      size_t iq = (size_t)(r0 + q)*256 + r0 + t;
      double xq = Q[ip], yq = Q[iq];
      Q[ip] = c*xq + s*yq;
      Q[iq] = c*yq - s*xq;
    }
  }
  if (t < K) w2[t] = rho*wv[t]*wv[t];
  __syncthreads();
  // secular roots: bisection in gap-relative coordinates (64 iters == f64-exact)
  if (t < K) {
    double dj = dlam[t];
    double hi0 = (t < K-1) ? (dlam[t+1] - dj) : rho*sumw2;
    double lo = 0.0, hi = hi0;
    for (int it = 0; it < 64; ++it) {
      double mid = 0.5*(lo + hi);
      double f = 1.0;
      for (int j2 = 0; j2 < K; ++j2) f += w2[j2]/((dlam[j2] - dj) - mid);
      if (f < 0.0) lo = mid; else hi = mid;
    }
    double tl = 0.5*(lo + hi);
    if (tl <= 0.0) tl = hi0*1e-300;
    tauv[t] = tl;
  }
  __syncthreads();
  // Gu-Eisenstat zhat (dlaed3)
  if (t < K) {
    double dt2 = dlam[t], p = tauv[t];
    for (int i = 0; i < K; ++i) { if (i == t) continue; double del = dlam[i] - dt2; p *= (del + tauv[i])/del; }
    zh[t] = copysign(sqrt(fabs(p)), wv[t]);
  }
  __syncthreads();
  // S columns (normalized); row-i writes coalesced across t
  if (t < K) {
    double dj = dlam[t], tj = tauv[t];
    double nrm = 0.0;
    for (int i = 0; i < K; ++i) { double sij = zh[i]/((dlam[i] - dj) - tj); nrm += sij*sij; }
    double inv = 1.0/sqrt(nrm);
    for (int i = 0; i < K; ++i) Sg[(size_t)(r0 + i)*256 + t] = (zh[i]/((dlam[i] - dj) - tj))*inv;
  }
  __syncthreads();
  // final ordering dlamrg(K asc, deflated desc-backward)
  if (t == 0) {
    int i = 0, p = nn - 1, f = 0;
    while (f < nn) {
      bool takesec;
      if (i < K && p >= K2) takesec = ((dlam[i] + tauv[i]) <= dloc[indxp[p]]);
      else takesec = (i < K);
      if (takesec) { dfin[f] = dlam[i] + tauv[i]; permf[f] = i; i++; }
      else         { dfin[f] = dloc[indxp[p]];    permf[f] = K + (p - K2); p--; }
      f++;
    }
    for (f = 0; f < nn; ++f) DW[b*256 + r0 + f] = dfin[f];
    meta[0] = K; meta[1] = K2;
  }
  __syncthreads();
  if (t < nn) { meta[2 + t] = indxp[t]; meta[258 + t] = permf[t]; }
}

// ================= merge phase 2: QNT[j][r] = sum_i S[i][j] * QT[indxp[i]][r] (LDS-tiled) + deflated copy =================
__global__ __launch_bounds__(256) void k_mgemm(int n1, int nmrg, const double* __restrict__ QT,
        const double* __restrict__ SG, const int* __restrict__ META, double* __restrict__ QNT) {
  int nn = 2*n1;
  int jt = blockIdx.x, rt = blockIdx.y;
  int z = blockIdx.z;
  int mrg = z % nmrg, b = z / nmrg;
  int r0 = mrg*nn;
  int t = threadIdx.x;
  const int* meta = META + ((b*8 + mrg)*520);
  __shared__ int sindxp[256];
  __shared__ double Gs[32][66];
  __shared__ double Ss[32][33];
  const double* Q = QT + (size_t)b*65536;
  const double* Sg = SG + (size_t)b*65536;
  double* Qn = QNT + (size_t)b*65536;
  int K = meta[0], K2 = meta[1];
  if (t < nn) sindxp[t] = meta[2 + t];
  __syncthreads();
  int jl = t >> 6, rl = t & 63;
  int r = rt*64 + rl;
  double acc[8];
  #pragma unroll
  for (int q = 0; q < 8; ++q) acc[q] = 0.0;
  if (jt*32 < K) {
    for (int i0 = 0; i0 < K; i0 += 32) {
      // stage G tile: rows = gathered eigvec indices, cols = components
      #pragma unroll
      for (int w = 0; w < 8; ++w) {
        int idx = t + 256*w;
        int ii = idx >> 6, rr = idx & 63;
        double v = 0.0;
        if (i0 + ii < K && rt*64 + rr < nn)
          v = Q[(size_t)(r0 + sindxp[i0 + ii])*256 + r0 + rt*64 + rr];
        Gs[ii][rr] = v;
      }
      // stage S tile
      #pragma unroll
      for (int w = 0; w < 4; ++w) {
        int idx = t + 256*w;
        int ii2 = idx >> 5, jj = idx & 31;
        double v = 0.0;
        if (i0 + ii2 < K)
          v = Sg[(size_t)(r0 + i0 + ii2)*256 + jt*32 + jj];
        Ss[ii2][jj] = v;
      }
      __syncthreads();
      int kmax = (K - i0 < 32) ? (K - i0) : 32;
      for (int ii = 0; ii < kmax; ++ii) {
        double gv = Gs[ii][rl];
        #pragma unroll
        for (int q = 0; q < 8; ++q) acc[q] += Ss[ii][jl + 4*q] * gv;
      }
      __syncthreads();
    }
  }
  if (r < nn) {
    #pragma unroll
    for (int q = 0; q < 8; ++q) {
      int j = jt*32 + jl + 4*q;
      if (j < K) Qn[(size_t)(r0 + j)*256 + r0 + r] = acc[q];
      else if (j < nn) {
        int p = K2 + (j - K);
        Qn[(size_t)(r0 + j)*256 + r0 + r] = Q[(size_t)(r0 + sindxp[p])*256 + r0 + r];
      }
    }
  }
}

// ================= merge phase 3: permute rows back into QT =================
__global__ __launch_bounds__(256) void k_mperm(int n1, const double* __restrict__ QNT,
        const int* __restrict__ META, double* __restrict__ QT) {
  int mrg = blockIdx.x, b = blockIdx.y, t = threadIdx.x;
  int nn = 2*n1, r0 = mrg*nn;
  const int* meta = META + ((b*8 + mrg)*520);
  __shared__ int pf[256];
  if (t < nn) pf[t] = meta[258 + t];
  __syncthreads();
  if (t < nn) {
    for (int f = 0; f < nn; ++f)
      QT[(size_t)b*65536 + (size_t)(r0 + f)*256 + r0 + t] =
        QNT[(size_t)b*65536 + (size_t)(r0 + pf[f])*256 + r0 + t];
  }
}

// ================= back-transform on QT rows: eigvec t gets H(1)..H(254) applied =================
__global__ __launch_bounds__(256) void k_backxf(const double* __restrict__ A, const double* __restrict__ tau_g,
        double* __restrict__ QT) {
  int b = blockIdx.x, t = threadIdx.x;
  const double* Ab = A + (size_t)b*65536;
  double* Z = QT + (size_t)b*65536 + (size_t)t*256;   // this thread's eigenvector (contiguous row)
  __shared__ double vL[256];
  for (int s = 253; s >= 0; --s) {
    double tauv = tau_g[b*256 + s];
    if (t == 0) vL[s+1] = 1.0;
    int r = s + 2 + t;
    if (r < 256) vL[r] = Ab[s*256 + r];
    __syncthreads();
    if (tauv != 0.0) {
      double w = 0.0;
      for (int rr = s + 1; rr < 256; ++rr) w += vL[rr]*Z[rr];
      double tw = tauv*w;
      for (int rr = s + 1; rr < 256; ++rr) Z[rr] -= tw*vL[rr];
    }
    __syncthreads();
  }
}

__global__ __launch_bounds__(256) void k_vt(const double* __restrict__ QT, float* __restrict__ Vt) {
  int c = blockIdx.x, b = blockIdx.y, t = threadIdx.x;
  Vt[((size_t)b*256 + c)*256 + t] = (float)QT[(size_t)b*65536 + (size_t)c*256 + t];
}

// ================= x_proj = V x, + x, fused maxpool + noise output =================
__global__ __launch_bounds__(256) void k_xproj(const float* __restrict__ x, const float* __restrict__ Vt,
        float* __restrict__ xp, float* __restrict__ noise_out) {
  int R = blockIdx.x, ct = blockIdx.y, b = blockIdx.z;
  int t = threadIdx.x;
  int cl = t >> 3, l8 = t & 7;
  __shared__ float vsh[32][20];
  __shared__ float xs[16][520];
  const float* xb = x + (size_t)b*256*NPX;
  int s0 = R*512;
  float acc[64];
  #pragma unroll
  for (int p = 0; p < 64; ++p) acc[p] = 0.0f;
  for (int d0 = 0; d0 < 256; d0 += 16) {
    for (int q = t; q < 512; q += 256) {
      int c = q >> 4, dd = q & 15;
      vsh[c][dd] = Vt[((size_t)b*256 + ct*32 + c)*256 + d0 + dd];
    }
    for (int q = t; q < 8192; q += 256) {
      int dd = q >> 9, px = q & 511;
      xs[dd][px] = xb[(size_t)(d0 + dd)*NPX + s0 + px];
    }
    __syncthreads();
    for (int dd = 0; dd < 16; ++dd) {
      float a = vsh[cl][dd];
      const float* xr = &xs[dd][l8];
      #pragma unroll
      for (int p = 0; p < 64; ++p) acc[p] += a*xr[8*p];
    }
    __syncthreads();
  }
  int cg = ct*32 + cl;
  const float* xc = xb + (size_t)cg*NPX + s0;
  float vmax[16];
  #pragma unroll
  for (int j = 0; j < 16; ++j) vmax[j] = -3.0e38f;
  bool isnz = (ct == 0);
  #pragma unroll
  for (int p = 0; p < 64; ++p) {
    int px = l8 + 8*p;
    float val = acc[p] + xc[px];
    vmax[p & 15] = fmaxf(vmax[p & 15], val);
    if (isnz) noise_out[((size_t)b*32 + cl)*NPX + s0 + px] = val;
  }
  #pragma unroll
  for (int j = 0; j < 16; ++j) {
    float v = vmax[j];
    v = fmaxf(v, __shfl_xor(v, 1));
    v = fmaxf(v, __shfl_xor(v, 2));
    vmax[j] = v;
  }
  if ((l8 & 3) == 0) {
    int halfsel = l8 >> 2;
    #pragma unroll
    for (int j = 0; j < 16; ++j)
      xp[((size_t)b*256 + cg)*PPX + R*32 + 2*j + halfsel] = vmax[j];
  }
}

// ================= qkv 1x1 conv (672 needed rows) =================
__global__ __launch_bounds__(256) void k_qkv(const float* __restrict__ xp, const float* __restrict__ wq,
        const float* __restrict__ bq, float* __restrict__ qkvm) {
  int pt = blockIdx.x, ot = blockIdx.y, b = blockIdx.z;
  int t = threadIdx.x;
  int ol = t & 31, pg = t >> 5;
  __shared__ float wsh[32][9];
  __shared__ float xsh[8][260];
  float acc[32];
  #pragma unroll
  for (int j = 0; j < 32; ++j) acc[j] = 0.0f;
  for (int ic0 = 0; ic0 < 256; ic0 += 8) {
    {
      int o = t >> 3, j = t & 7;
      int orow = ot*32 + o;
      int reg = orow/224, rem = orow - reg*224;
      int wrow = 32 + rem + 256*reg;
      wsh[o][j] = wq[(size_t)wrow*256 + ic0 + j];
    }
    for (int q = t; q < 2048; q += 256) {
      int ic = q >> 8, px = q & 255;
      xsh[ic][px] = xp[((size_t)b*256 + ic0 + ic)*PPX + pt*256 + px];
    }
    __syncthreads();
    for (int ic = 0; ic < 8; ++ic) {
      float a = wsh[ol][ic];
      const float* xr = &xsh[ic][pg];
      #pragma unroll
      for (int j = 0; j < 32; ++j) acc[j] += a*xr[8*j];
    }
    __syncthreads();
  }
  int orow = ot*32 + ol;
  int reg = orow/224, rem = orow - reg*224;
  float bv = bq[32 + rem + 256*reg];
  #pragma unroll
  for (int j = 0; j < 32; ++j)
    qkvm[((size_t)b*672 + orow)*PPX + pt*256 + pg + 8*j] = acc[j] + bv;
}

// ================= attention =================
__global__ __launch_bounds__(256) void k_attn(const float* __restrict__ qkvm, const float* __restrict__ emb,
        const float* __restrict__ xp, float* __restrict__ pool) {
  int rt = blockIdx.x, n = blockIdx.y, b = blockIdx.z;
  int t = threadIdx.x;
  int rl = t >> 5, pg = t & 31;
  __shared__ float S[8][1032];
  __shared__ float qsh[8][33];
  __shared__ float kv[4224];
  const float* qb = qkvm + (size_t)b*672*PPX;
  int rg0 = rt*8;
  {
    int rg = rg0 + rl;
    float qv = qb[(size_t)(32*n + (rg >> 5))*PPX + ((rg & 31) << 5) + pg];
    float ev = emb[(((size_t)n*8 + b)*1024 + rg)*32 + pg];
    qsh[rl][pg] = (qv + ev)*0.17677669529663688f;
  }
  __syncthreads();
  const float* kb = qb + (size_t)(224 + 32*n)*PPX;
  for (int p0 = 0; p0 < 1024; p0 += 128) {
    for (int q = t; q < 4096; q += 256) {
      int c = q >> 7, pp = q & 127;
      kv[c*132 + pp] = kb[(size_t)c*PPX + p0 + pp];
    }
    __syncthreads();
    float a0 = 0, a1 = 0, a2 = 0, a3 = 0;
    for (int c = 0; c < 32; ++c) {
      float qv = qsh[rl][c];
      const float* kr = &kv[c*132 + pg];
      a0 += qv*kr[0]; a1 += qv*kr[32]; a2 += qv*kr[64]; a3 += qv*kr[96];
    }
    S[rl][p0 + pg]      = a0;
    S[rl][p0 + pg + 32] = a1;
    S[rl][p0 + pg + 64] = a2;
    S[rl][p0 + pg + 96] = a3;
    __syncthreads();
  }
  float mx = -3.0e38f;
  for (int j = 0; j < 32; ++j) mx = fmaxf(mx, S[rl][pg + 32*j]);
  #pragma unroll
  for (int m = 1; m <= 16; m <<= 1) mx = fmaxf(mx, __shfl_xor(mx, m));
  float sum = 0.0f;
  for (int j = 0; j < 32; ++j) {
    float e = expf(S[rl][pg + 32*j] - mx);
    S[rl][pg + 32*j] = e;
    sum += e;
  }
  #pragma unroll
  for (int m = 1; m <= 16; m <<= 1) sum += __shfl_xor(sum, m);
  float inv = 1.0f/sum;
  for (int j = 0; j < 32; ++j) S[rl][pg + 32*j] *= inv;
  __syncthreads();
  const float* vb = qb + (size_t)(448 + 32*n)*PPX;
  float acc = 0.0f;
  for (int p0 = 0; p0 < 1024; p0 += 128) {
    for (int q = t; q < 4096; q += 256) {
      int pp = q >> 5, c = q & 31;
      int p = p0 + pp;
      kv[pp*33 + c] = vb[(size_t)(p >> 5)*PPX + ((p & 31) << 5) + c];
    }
    __syncthreads();
    for (int pp = 0; pp < 128; ++pp) acc += S[rl][p0 + pp]*kv[pp*33 + pg];
    __syncthreads();
  }
  int rg = rg0 + rl;
  int ch = 32*n + (rg >> 5);
  size_t sp = (size_t)((rg & 31) << 5) + pg;
  pool[((size_t)b*224 + ch)*PPX + sp] = acc + xp[((size_t)b*256 + 32 + ch)*PPX + sp];
}

__global__ void k_owt(const float* __restrict__ ow, float* __restrict__ owt) {
  int t = blockIdx.x*256 + threadIdx.x;
  if (t < 256*224) {
    int oc = t/224, ch = t - oc*224;
    owt[(size_t)ch*256 + oc] = ow[t];
  }
}

// ================= bilinear + sim gating + final conv =================
__global__ __launch_bounds__(256) void k_final(const float* __restrict__ pool, const float* __restrict__ noise,
        const float* __restrict__ sim_w, const float* __restrict__ owt, float* __restrict__ out) {
  int tt = blockIdx.x, b = blockIdx.y;
  int t = threadIdx.x;
  int h = tt >> 3, w0 = (tt & 7)*16;
  __shared__ float xa[224][20];
  __shared__ float nsc[224][20];
  __shared__ float nz[32][20];
  __shared__ float scl[16];
  for (int q = t; q < 512; q += 256) {
    int c = q >> 4, px = q & 15;
    nz[c][px] = noise[((size_t)b*32 + c)*NPX + h*128 + w0 + px];
  }
  float hs = h*0.25f - 0.375f;
  float hf = floorf(hs);
  int h0 = (int)hf;
  float fh = hs - hf;
  int h0c = min(max(h0, 0), 31);
  int h1c = min(max(h0 + 1, 0), 31);
  __syncthreads();
  for (int q = t; q < 3584; q += 256) {
    int c = q >> 4, px = q & 15;
    int w = w0 + px;
    float wsrc = w*0.25f - 0.375f;
    float wf = floorf(wsrc);
    int W0 = (int)wf;
    float fw = wsrc - wf;
    int w0c = min(max(W0, 0), 31);
    int w1c = min(max(W0 + 1, 0), 31);
    const float* pb = pool + ((size_t)b*224 + c)*PPX;
    float v00 = pb[h0c*32 + w0c], v01 = pb[h0c*32 + w1c];
    float v10 = pb[h1c*32 + w0c], v11 = pb[h1c*32 + w1c];
    xa[c][px] = (1.0f - fh)*((1.0f - fw)*v00 + fw*v01) + fh*((1.0f - fw)*v10 + fw*v11);
    float np = 0.0f;
    #pragma unroll
    for (int j = 0; j < 32; ++j) np += sim_w[c*32 + j]*nz[j][px];
    nsc[c][px] = np;
  }
  __syncthreads();
  {
    int px = t >> 4, kk = t & 15;
    float s1 = 0, s2 = 0, s3 = 0;
    for (int c = kk; c < 224; c += 16) {
      float a = xa[c][px], p = nsc[c][px];
      s1 += a*a; s2 += p*p; s3 += a*p;
    }
    #pragma unroll
    for (int m = 1; m <= 8; m <<= 1) {
      s1 += __shfl_xor(s1, m);
      s2 += __shfl_xor(s2, m);
      s3 += __shfl_xor(s3, m);
    }
    if (kk == 0) {
      float n1 = fmaxf(sqrtf(s1), 1e-12f);
      float n2 = fmaxf(sqrtf(s2), 1e-12f);
      float sim = (s3/(n1*n2) + 1.0f)*0.5f;
      scl[px] = 1.0f - sim;
    }
  }
  __syncthreads();
  {
    float accp[16];
    #pragma unroll
    for (int px = 0; px < 16; ++px) accp[px] = 0.0f;
    for (int c = 0; c < 224; ++c) {
      float wv = owt[(size_t)c*256 + t];
      #pragma unroll
      for (int px = 0; px < 16; ++px) accp[px] += wv*xa[c][px];
    }
    size_t obase = ((size_t)b*256 + t)*NPX + (size_t)h*128 + w0;
    #pragma unroll
    for (int px = 0; px < 16; ++px) out[obase + px] = accp[px]*scl[px];
  }
  if (b == 0 && tt == 0 && t == 0) out[(size_t)33554432] = 8.0f;   // AVG_K
}

extern "C" void kernel_launch(void* const* d_in, const int* in_sizes, int n_in,
                              void* d_out, int out_size, void* d_ws, size_t ws_size,
                              hipStream_t stream) {
  (void)in_sizes; (void)n_in; (void)out_size; (void)ws_size;
  const float* x     = (const float*)d_in[0];
  const float* qkv_w = (const float*)d_in[1];
  const float* qkv_b = (const float*)d_in[2];
  const float* emb   = (const float*)d_in[3];
  const float* sim_w = (const float*)d_in[4];
  const float* out_w = (const float*)d_in[5];
  float* out = (float*)d_out;
  char* ws = (char*)d_ws;
  double* gram = (double*)(ws + OFF_GRAM);
  double* A    = (double*)(ws + OFF_A);
  double* QT   = (double*)(ws + OFF_QT);
  double* SG   = (double*)(ws + OFF_SG);
  double* QNT  = (double*)(ws + OFF_QN);
  double* d_a  = (double*)(ws + OFF_D);
  double* e_a  = (double*)(ws + OFF_E);
  double* tau_a= (double*)(ws + OFF_TAU);
  double* DW   = (double*)(ws + OFF_DW);
  int*    META = (int*)   (ws + OFF_META);
  float*  Vt   = (float*) (ws + OFF_VT);
  float*  xp   = (float*) (ws + OFF_XP);
  float*  qkvm = (float*) (ws + OFF_QKV);
  float*  pool = (float*) (ws + OFF_POOL);
  float*  owt  = (float*) (ws + OFF_OWT);
  float*  noise_out = out + 33554433;

  k_gram   <<<dim3(8,8,8),   256, 0, stream>>>(x, gram);
  k_tridiag<<<dim3(8),       256, 0, stream>>>(gram, A, d_a, e_a, tau_a);
  k_zeroq  <<<dim3(512),     256, 0, stream>>>(QT);
  k_leaves <<<dim3(8),       64,  0, stream>>>(d_a, e_a, QT, DW);
  // merge levels: n1 = 16, 32, 64, 128; nmrg = 8, 4, 2, 1
  {
    const int n1s[4]   = {16, 32, 64, 128};
    const int nmrgs[4] = {8, 4, 2, 1};
    for (int lv = 0; lv < 4; ++lv) {
      int n1 = n1s[lv], nmrg = nmrgs[lv], nn = 2*n1;
      k_mscan<<<dim3(nmrg, 8), 256, 0, stream>>>(n1, e_a, QT, DW, SG, META);
      k_mgemm<<<dim3(nn/32, (nn + 63)/64, nmrg*8), 256, 0, stream>>>(n1, nmrg, QT, SG, META, QNT);
      k_mperm<<<dim3(nmrg, 8), 256, 0, stream>>>(n1, QNT, META, QT);
    }
  }
  k_backxf <<<dim3(8),       256, 0, stream>>>(A, tau_a, QT);
  k_vt     <<<dim3(256,8),   256, 0, stream>>>(QT, Vt);
  k_xproj  <<<dim3(32,8,8),  256, 0, stream>>>(x, Vt, xp, noise_out);
  k_qkv    <<<dim3(4,21,8),  256, 0, stream>>>(xp, qkv_w, qkv_b, qkvm);
  k_attn   <<<dim3(128,7,8), 256, 0, stream>>>(qkvm, emb, xp, pool);
  k_owt    <<<dim3(224),     256, 0, stream>>>(out_w, owt);
  k_final  <<<dim3(1024,8),  256, 0, stream>>>(pool, noise_out, sim_w, owt, out);
}

// Round 7
// 12942.532 us; speedup vs baseline: 1.8426x; 1.5059x over previous
//
#include <hip/hip_runtime.h>
#include <math.h>

#define NB  8
#define NPX 16384   // 128*128
#define PPX 1024    // 32*32

// f32 LAPACK machine constants (SLAMCH) used for branch tolerances
#define EPS32   5.9604644775390625e-8   // 2^-24 (slamch 'E')
#define EPS232  (EPS32*EPS32)
#define SAFMIN32 1.1754943508222875e-38

// ---------------- workspace layout (bytes), phase-aliased ----------------
static constexpr size_t OFF_VT   = 0;                    // f32 [8][256][256] 2MB (lives across phases)
static constexpr size_t U        = 0x200000;
static constexpr size_t OFF_GRAM = U;                    // f64 [8][256][256] 4MB
static constexpr size_t OFF_A    = U + 0x400000;         // f64 [8][256][256] 4MB reflectors
static constexpr size_t OFF_QT   = U + 0x800000;         // f64 [8][256][256] 4MB QT[col][row] (tridiag eigvecs, transposed)
static constexpr size_t OFF_SG   = U + 0xC00000;         // f64 [8][256][256] 4MB S scratch
static constexpr size_t OFF_QN   = U + 0x1000000;        // f64 [8][256][256] 4MB QNT scratch
static constexpr size_t OFF_D    = U + 0x1400000;        // f64 [8][256]
static constexpr size_t OFF_E    = U + 0x1404000;        // f64 [8][256]
static constexpr size_t OFF_TAU  = U + 0x1408000;        // f64 [8][256]
static constexpr size_t OFF_DW   = U + 0x140C000;        // f64 [8][256] working eigenvalues
static constexpr size_t OFF_META = U + 0x1410000;        // int [8][8][520]  K,K2,indxp[256],permf[256]
// phase2 aliases (phase1 dead in order: GRAM after tridiag, A/QT after backxf, SG/QN/META after merges):
static constexpr size_t OFF_XP   = U;                    // f32 [8][256][1024] 8MB
static constexpr size_t OFF_QKV  = U + 0x800000;         // f32 [8][672][1024] 21MB
static constexpr size_t OFF_POOL = U + 0x1D00000;        // f32 [8][224][1024] 7MB
static constexpr size_t OFF_OWT  = U + 0x2400000;        // f32 [224][256]

// ================= gram = X X^T (f64 accumulate) =================
__global__ __launch_bounds__(256) void k_gram(const float* __restrict__ x, double* __restrict__ gram) {
  int jt = blockIdx.x, it = blockIdx.y, b = blockIdx.z;
  __shared__ float xi[32][129], xj[32][129];
  const float* xb = x + (size_t)b*256*NPX;
  int t = threadIdx.x;
  int ci = t & 31, cjg = t >> 5;
  double acc[4] = {0.0,0.0,0.0,0.0};
  for (int n0 = 0; n0 < NPX; n0 += 128) {
    for (int q = 0; q < 16; ++q) {
      int idx = t + q*256;
      int r = idx >> 7, cc = idx & 127;
      xi[r][cc] = xb[(size_t)(it*32 + r)*NPX + n0 + cc];
      xj[r][cc] = xb[(size_t)(jt*32 + r)*NPX + n0 + cc];
    }
    __syncthreads();
    for (int p = 0; p < 128; ++p) {
      double a = (double)xi[ci][p];
      #pragma unroll
      for (int k = 0; k < 4; ++k) acc[k] += a * (double)xj[cjg + 8*k][p];
    }
    __syncthreads();
  }
  #pragma unroll
  for (int k = 0; k < 4; ++k)
    gram[((size_t)b*256 + it*32 + ci)*256 + jt*32 + cjg + 8*k] = acc[k];
}

__device__ __forceinline__ double blkSum(double v, double* tmp, int t) {
  #pragma unroll
  for (int m = 1; m <= 32; m <<= 1) v += __shfl_xor(v, m);
  __syncthreads();
  if ((t & 63) == 0) tmp[t >> 6] = v;
  __syncthreads();
  return tmp[0] + tmp[1] + tmp[2] + tmp[3];
}

// ================= Householder tridiagonalization (dsytd2 'L', f64) =================
__global__ __launch_bounds__(256) void k_tridiag(const double* __restrict__ gram, double* __restrict__ A,
        double* __restrict__ d_g, double* __restrict__ e_g, double* __restrict__ tau_g) {
  int b = blockIdx.x, t = threadIdx.x;
  const double* gb = gram + (size_t)b*65536;
  double* Ab = A + (size_t)b*65536;
  __shared__ double vL[256], wL[256];
  __shared__ double tmp[4];
  for (int q = 0; q < 256; ++q) Ab[q*256 + t] = gb[q*256 + t];
  __syncthreads();
  for (int i = 0; i < 255; ++i) {
    double part = 0.0;
    int rx = i + 2 + t;
    if (rx < 256) { double v = Ab[i*256 + rx]; part = v*v; }
    double xn2 = blkSum(part, tmp, t);
    double alpha = Ab[i*256 + i + 1];
    double beta, tauv, scale;
    if (xn2 == 0.0) { beta = alpha; tauv = 0.0; scale = 0.0; }
    else {
      beta  = -copysign(sqrt(alpha*alpha + xn2), alpha);   // dlarfg
      tauv  = (beta - alpha)/beta;
      scale = 1.0/(alpha - beta);
    }
    if (t == 0) { e_g[b*256 + i] = beta; tau_g[b*256 + i] = tauv; vL[i+1] = 1.0; }
    if (rx < 256) {
      double v = Ab[i*256 + rx] * scale;
      vL[rx] = v;
      Ab[i*256 + rx] = v;                 // store v in row i for back-transform
    }
    __syncthreads();
    if (tauv != 0.0) {
      int c = i + 1 + t;
      double w = 0.0;
      if (c < 256) {
        for (int r = i + 1; r < 256; ++r) w += Ab[r*256 + c] * vL[r];
        w *= tauv;
        wL[c] = w;
      }
      double part2 = (c < 256) ? vL[c]*w : 0.0;
      double dot = blkSum(part2, tmp, t);
      double coef = -0.5*tauv*dot;
      if (c < 256) wL[c] = w + coef*vL[c];
      __syncthreads();
      if (c < 256) {
        double vc = vL[c], wc = wL[c];
        for (int r = i + 1; r < 256; ++r)
          Ab[r*256 + c] = Ab[r*256 + c] - vL[r]*wc - wL[r]*vc;
      }
      __syncthreads();
    } else {
      __syncthreads();
    }
  }
  d_g[b*256 + t] = Ab[t*256 + t];
  if (t == 0) e_g[b*256 + 255] = 0.0;
}

// ================= LAPACK helpers =================
__device__ __forceinline__ void dlartg_(double f, double g, double& c, double& s, double& r) {
  if (g == 0.0) { c = 1.0; s = 0.0; r = f; }
  else if (f == 0.0) { c = 0.0; s = (g > 0.0) ? 1.0 : -1.0; r = fabs(g); }
  else {
    double d = sqrt(f*f + g*g);
    r = (f >= 0.0) ? d : -d;
    c = f / r;
    s = g / r;
  }
}

__device__ void dlaev2_(double a, double b, double cc, double& rt1, double& rt2, double& cs1, double& sn1) {
  double sm = a + cc, df = a - cc;
  double adf = fabs(df), tb = b + b, ab = fabs(tb);
  double acmx, acmn;
  if (fabs(a) > fabs(cc)) { acmx = a; acmn = cc; } else { acmx = cc; acmn = a; }
  double rt;
  if (adf > ab)      rt = adf*sqrt(1.0 + (ab/adf)*(ab/adf));
  else if (adf < ab) rt = ab*sqrt(1.0 + (adf/ab)*(adf/ab));
  else               rt = ab*sqrt(2.0);
  int sgn1;
  if (sm < 0.0)      { rt1 = 0.5*(sm - rt); sgn1 = -1; rt2 = (acmx/rt1)*acmn - (b/rt1)*b; }
  else if (sm > 0.0) { rt1 = 0.5*(sm + rt); sgn1 = 1;  rt2 = (acmx/rt1)*acmn - (b/rt1)*b; }
  else               { rt1 = 0.5*rt; rt2 = -0.5*rt; sgn1 = 1; }
  double cs; int sgn2;
  if (df >= 0.0) { cs = df + rt; sgn2 = 1; } else { cs = df - rt; sgn2 = -1; }
  double acs = fabs(cs);
  if (acs > ab) {
    double ct = -tb/cs;
    sn1 = 1.0/sqrt(1.0 + ct*ct);
    cs1 = ct*sn1;
  } else {
    if (ab == 0.0) { cs1 = 1.0; sn1 = 0.0; }
    else {
      double tn = -cs/tb;
      cs1 = 1.0/sqrt(1.0 + tn*tn);
      sn1 = tn*cs1;
    }
  }
  if (sgn1 == sgn2) { double tn = cs1; cs1 = -sn1; sn1 = tn; }
}

// faithful dsteqr('I') on an n<=16 block, f64 arithmetic with f32 tolerances
__device__ void steqr_leaf(int n, double* d, double* e, double* q, int ldq) {
  const double eps = EPS32, eps2 = EPS232, safmin = SAFMIN32;
  int nmaxit = n*30, jtot = 0;
  int l1 = 0;
  while (l1 < n) {
    if (l1 > 0) e[l1-1] = 0.0;
    int m;
    for (m = l1; m < n-1; ++m) {
      double tst = fabs(e[m]);
      if (tst == 0.0) break;
      if (tst <= (sqrt(fabs(d[m]))*sqrt(fabs(d[m+1])))*eps) { e[m] = 0.0; break; }
    }
    int l = l1, lend = m;
    l1 = m + 1;
    if (lend == l) continue;
    if (fabs(d[lend]) < fabs(d[l])) { int tsw = l; l = lend; lend = tsw; }
    if (lend > l) {
      while (true) {
        int mm;
        for (mm = l; mm < lend; ++mm) {
          double tst = e[mm]*e[mm];
          if (tst <= (eps2*fabs(d[mm]))*fabs(d[mm+1]) + safmin) break;
        }
        if (mm < lend) e[mm] = 0.0;
        double p = d[l];
        if (mm == l) { l = l + 1; if (l > lend) break; continue; }
        if (mm == l+1) {
          double rt1, rt2, c, s;
          dlaev2_(d[l], e[l], d[l+1], rt1, rt2, c, s);
          for (int i = 0; i < n; ++i) {
            double t1 = q[i*ldq + l+1], t0 = q[i*ldq + l];
            q[i*ldq + l+1] = c*t1 - s*t0;
            q[i*ldq + l]   = s*t1 + c*t0;
          }
          d[l] = rt1; d[l+1] = rt2; e[l] = 0.0;
          l += 2; if (l > lend) break; continue;
        }
        if (jtot == nmaxit) break;
        jtot++;
        double g = (d[l+1] - p)/(2.0*e[l]);
        double r = sqrt(g*g + 1.0);
        g = d[mm] - p + e[l]/(g + copysign(r, g));
        double s = 1.0, c = 1.0; p = 0.0;
        double csv[16], snv[16];
        for (int i = mm-1; i >= l; --i) {
          double f = s*e[i], bb = c*e[i];
          dlartg_(g, f, c, s, r);
          if (i != mm-1) e[i+1] = r;
          g = d[i+1] - p;
          r = (d[i] - g)*s + 2.0*c*bb;
          p = s*r;
          d[i+1] = g + p;
          g = c*r - bb;
          csv[i] = c; snv[i] = -s;
        }
        for (int i = mm-1; i >= l; --i) {
          double cc2 = csv[i], ss2 = snv[i];
          for (int k = 0; k < n; ++k) {
            double t1 = q[k*ldq + i+1], t0 = q[k*ldq + i];
            q[k*ldq + i+1] = cc2*t1 - ss2*t0;
            q[k*ldq + i]   = ss2*t1 + cc2*t0;
          }
        }
        d[l] -= p; e[l] = g;
      }
    } else {
      while (true) {
        int mm;
        for (mm = l; mm > lend; --mm) {
          double tst = e[mm-1]*e[mm-1];
          if (tst <= (eps2*fabs(d[mm]))*fabs(d[mm-1]) + safmin) break;
        }
        if (mm > lend) e[mm-1] = 0.0;
        double p = d[l];
        if (mm == l) { l = l - 1; if (l < lend) break; continue; }
        if (mm == l-1) {
          double rt1, rt2, c, s;
          dlaev2_(d[l-1], e[l-1], d[l], rt1, rt2, c, s);
          for (int i = 0; i < n; ++i) {
            double t1 = q[i*ldq + l], t0 = q[i*ldq + l-1];
            q[i*ldq + l]   = c*t1 - s*t0;
            q[i*ldq + l-1] = s*t1 + c*t0;
          }
          d[l-1] = rt1; d[l] = rt2; e[l-1] = 0.0;
          l -= 2; if (l < lend) break; continue;
        }
        if (jtot == nmaxit) break;
        jtot++;
        double g = (d[l-1] - p)/(2.0*e[l-1]);
        double r = sqrt(g*g + 1.0);
        g = d[mm] - p + e[l-1]/(g + copysign(r, g));
        double s = 1.0, c = 1.0; p = 0.0;
        double csv[16], snv[16];
        for (int i = mm; i <= l-1; ++i) {
          double f = s*e[i], bb = c*e[i];
          dlartg_(g, f, c, s, r);
          if (i != mm) e[i-1] = r;
          g = d[i] - p;
          r = (d[i+1] - g)*s + 2.0*c*bb;
          p = s*r;
          d[i] = g + p;
          g = c*r - bb;
          csv[i] = c; snv[i] = s;
        }
        for (int i = mm; i <= l-1; ++i) {
          double cc2 = csv[i], ss2 = snv[i];
          for (int k = 0; k < n; ++k) {
            double t1 = q[k*ldq + i+1], t0 = q[k*ldq + i];
            q[k*ldq + i+1] = cc2*t1 - ss2*t0;
            q[k*ldq + i]   = ss2*t1 + cc2*t0;
          }
        }
        d[l] -= p; e[l-1] = g;
      }
    }
  }
  for (int ii = 1; ii < n; ++ii) {
    int k = ii - 1; double p = d[k];
    for (int j = ii; j < n; ++j) if (d[j] < p) { k = j; p = d[j]; }
    if (k != ii-1) {
      d[k] = d[ii-1]; d[ii-1] = p;
      for (int r = 0; r < n; ++r) { double tq = q[r*ldq + ii-1]; q[r*ldq + ii-1] = q[r*ldq + k]; q[r*ldq + k] = tq; }
    }
  }
}

__global__ __launch_bounds__(256) void k_zeroq(double* __restrict__ QT) {
  size_t i = (size_t)blockIdx.x*256 + threadIdx.x;
  size_t total = (size_t)NB*65536;
  for (; i < total; i += (size_t)gridDim.x*256) QT[i] = 0.0;
}

// ================= leaves: tears + 16x ssteqr(16), write TRANSPOSED (QT[eigvec][component]) =================
__global__ __launch_bounds__(64) void k_leaves(const double* __restrict__ d_g, const double* __restrict__ e_g,
        double* __restrict__ QT, double* __restrict__ DW) {
  int b = blockIdx.x, t = threadIdx.x;
  __shared__ double dL[256], eL[256];
  __shared__ double ql[16*272];   // 16 leaves x [16][17]
  for (int i = t; i < 256; i += 64) { dL[i] = d_g[b*256 + i]; eL[i] = e_g[b*256 + i]; }
  __syncthreads();
  if (t == 0) {
    for (int cut = 16; cut < 256; cut += 16) {
      double a = fabs(eL[cut-1]);
      dL[cut-1] -= a; dL[cut] -= a;
    }
  }
  __syncthreads();
  if (t < 16) {
    double* q = &ql[t*272];
    for (int i = 0; i < 16; ++i)
      for (int j = 0; j < 16; ++j) q[i*17 + j] = (i == j) ? 1.0 : 0.0;
    steqr_leaf(16, dL + 16*t, eL + 16*t, q, 17);
  }
  __syncthreads();
  for (int idx = t; idx < 4096; idx += 64) {
    int lf = idx >> 8, i = (idx >> 4) & 15, j = idx & 15;
    QT[(size_t)b*65536 + (size_t)(lf*16 + j)*256 + lf*16 + i] = ql[lf*272 + i*17 + j];
  }
  for (int i = t; i < 256; i += 64) DW[b*256 + i] = dL[i];
}

// ================= merge phase 1: scan + rotations + secular + S (dlaed1/2/3 faithful) =================
__global__ __launch_bounds__(256) void k_mscan(int n1, const double* __restrict__ e_g,
        double* __restrict__ QT, double* __restrict__ DW, double* __restrict__ SG, int* __restrict__ META) {
  int mrg = blockIdx.x, b = blockIdx.y, t = threadIdx.x;
  int nn = 2*n1, r0 = mrg*nn;
  double* Q = QT + (size_t)b*65536;
  double* Sg = SG + (size_t)b*65536;
  int* meta = META + ((b*8 + mrg)*520);
  __shared__ double dloc[256], zloc[256], dlam[256], wv[256], w2[256], tauv[256], zh[256], dfin[256];
  __shared__ int indx[256], indxp[256], permf[256];
  __shared__ double rotc[256], rots[256];
  __shared__ short rotp[256], rotq[256];
  __shared__ int KK[3];
  __shared__ double sc[2];
  double rho_raw = e_g[b*256 + r0 + n1 - 1];
  if (t < nn) {
    dloc[t] = DW[b*256 + r0 + t];
    double zv = Q[(size_t)(r0 + t)*256 + r0 + ((t < n1) ? (n1 - 1) : n1)];
    if (t >= n1 && rho_raw < 0.0) zv = -zv;      // dlaed2
    zloc[t] = zv * 0.70710678118654752440;
  }
  __syncthreads();
  if (t == 0) {
    int i = 0, jj = n1, pos = 0;
    while (i < n1 && jj < nn) { if (dloc[i] <= dloc[jj]) indx[pos++] = i++; else indx[pos++] = jj++; }
    while (i < n1) indx[pos++] = i++;
    while (jj < nn) indx[pos++] = jj++;
    double maxd = 0.0, maxz = 0.0;
    for (int q2 = 0; q2 < nn; ++q2) { maxd = fmax(maxd, fabs(dloc[q2])); maxz = fmax(maxz, fabs(zloc[q2])); }
    double rho = fabs(2.0*rho_raw);
    double tol = 8.0*EPS32*fmax(maxd, maxz);
    int K = 0, K2 = nn, nrot = 0, pj = -1, j = 0;
    for (; j < nn; ++j) {
      int nj = indx[j];
      if (rho*fabs(zloc[nj]) <= tol) { K2--; indxp[K2] = nj; }
      else { pj = nj; break; }
    }
    if (pj >= 0) {
      for (++j; j < nn; ++j) {
        int nj = indx[j];
        if (rho*fabs(zloc[nj]) <= tol) { K2--; indxp[K2] = nj; }
        else {
          double s = zloc[pj], c = zloc[nj];
          double tau = sqrt(c*c + s*s);
          double tdf = dloc[nj] - dloc[pj];
          c /= tau; s = -s/tau;
          if (fabs(tdf*c*s) <= tol) {
            zloc[nj] = tau; zloc[pj] = 0.0;
            rotp[nrot] = (short)pj; rotq[nrot] = (short)nj; rotc[nrot] = c; rots[nrot] = s; nrot++;
            double tt2 = dloc[pj]*c*c + dloc[nj]*s*s;
            dloc[nj] = dloc[pj]*s*s + dloc[nj]*c*c;
            dloc[pj] = tt2;
            K2--;
            int ii2 = 1;
            while (K2 + ii2 <= nn - 1 && dloc[pj] < dloc[indxp[K2 + ii2]]) { indxp[K2+ii2-1] = indxp[K2+ii2]; ii2++; }
            indxp[K2+ii2-1] = pj;
            pj = nj;
          } else {
            dlam[K] = dloc[pj]; wv[K] = zloc[pj]; indxp[K] = pj; K++;
            pj = nj;
          }
        }
      }
      dlam[K] = dloc[pj]; wv[K] = zloc[pj]; indxp[K] = pj; K++;
    }
    double sumw2 = 0.0;
    for (int q2 = 0; q2 < K; ++q2) sumw2 += wv[q2]*wv[q2];
    KK[0] = K; KK[1] = K2; KK[2] = nrot; sc[0] = rho; sc[1] = sumw2;
  }
  __syncthreads();
  int K = KK[0], K2 = KK[1], nrot = KK[2];
  double rho = sc[0], sumw2 = sc[1];
  if (t < nn) {
    for (int k = 0; k < nrot; ++k) {
      int p = rotp[k], q = rotq[k];
      double c = rotc[k], s = rots[k];
      size_t ip = (size_t)(r0 + p)*256 + r0 + t;
      size_t iq = (size_t)(r0 + q)*256 + r0 + t;
      double xq = Q[ip], yq = Q[iq];
      Q[ip] = c*xq + s*yq;
      Q[iq] = c*yq - s*xq;
    }
  }
  if (t < K) w2[t] = rho*wv[t]*wv[t];
  __syncthreads();
  if (t < K) {
    double dj = dlam[t];
    double hi0 = (t < K-1) ? (dlam[t+1] - dj) : rho*sumw2;
    double lo = 0.0, hi = hi0;
    for (int it = 0; it < 64; ++it) {
      double mid = 0.5*(lo + hi);
      double f = 1.0;
      for (int j2 = 0; j2 < K; ++j2) f += w2[j2]/((dlam[j2] - dj) - mid);
      if (f < 0.0) lo = mid; else hi = mid;
    }
    double tl = 0.5*(lo + hi);
    if (tl <= 0.0) tl = hi0*1e-300;
    tauv[t] = tl;
  }
  __syncthreads();
  if (t < K) {
    double dt2 = dlam[t], p = tauv[t];
    for (int i = 0; i < K; ++i) { if (i == t) continue; double del = dlam[i] - dt2; p *= (del + tauv[i])/del; }
    zh[t] = copysign(sqrt(fabs(p)), wv[t]);
  }
  __syncthreads();
  if (t < K) {
    double dj = dlam[t], tj = tauv[t];
    double nrm = 0.0;
    for (int i = 0; i < K; ++i) { double sij = zh[i]/((dlam[i] - dj) - tj); nrm += sij*sij; }
    double inv = 1.0/sqrt(nrm);
    for (int i = 0; i < K; ++i) Sg[(size_t)(r0 + i)*256 + t] = (zh[i]/((dlam[i] - dj) - tj))*inv;
  }
  __syncthreads();
  if (t == 0) {
    int i = 0, p = nn - 1, f = 0;
    while (f < nn) {
      bool takesec;
      if (i < K && p >= K2) takesec = ((dlam[i] + tauv[i]) <= dloc[indxp[p]]);
      else takesec = (i < K);
      if (takesec) { dfin[f] = dlam[i] + tauv[i]; permf[f] = i; i++; }
      else         { dfin[f] = dloc[indxp[p]];    permf[f] = K + (p - K2); p--; }
      f++;
    }
    for (f = 0; f < nn; ++f) DW[b*256 + r0 + f] = dfin[f];
    meta[0] = K; meta[1] = K2;
  }
  __syncthreads();
  if (t < nn) { meta[2 + t] = indxp[t]; meta[258 + t] = permf[t]; }
}

// ================= merge phase 2: QNT[j][r] = sum_i S[i][j] * QT[indxp[i]][r] (LDS-tiled) + deflated copy =================
__global__ __launch_bounds__(256) void k_mgemm(int n1, int nmrg, const double* __restrict__ QT,
        const double* __restrict__ SG, const int* __restrict__ META, double* __restrict__ QNT) {
  int nn = 2*n1;
  int jt = blockIdx.x, rt = blockIdx.y;
  int z = blockIdx.z;
  int mrg = z % nmrg, b = z / nmrg;
  int r0 = mrg*nn;
  int t = threadIdx.x;
  const int* meta = META + ((b*8 + mrg)*520);
  __shared__ int sindxp[256];
  __shared__ double Gs[32][66];
  __shared__ double Ss[32][33];
  const double* Q = QT + (size_t)b*65536;
  const double* Sg = SG + (size_t)b*65536;
  double* Qn = QNT + (size_t)b*65536;
  int K = meta[0], K2 = meta[1];
  if (t < nn) sindxp[t] = meta[2 + t];
  __syncthreads();
  int jl = t >> 6, rl = t & 63;
  int r = rt*64 + rl;
  double acc[8];
  #pragma unroll
  for (int q = 0; q < 8; ++q) acc[q] = 0.0;
  if (jt*32 < K) {
    for (int i0 = 0; i0 < K; i0 += 32) {
      #pragma unroll
      for (int w = 0; w < 8; ++w) {
        int idx = t + 256*w;
        int ii = idx >> 6, rr = idx & 63;
        double v = 0.0;
        if (i0 + ii < K && rt*64 + rr < nn)
          v = Q[(size_t)(r0 + sindxp[i0 + ii])*256 + r0 + rt*64 + rr];
        Gs[ii][rr] = v;
      }
      #pragma unroll
      for (int w = 0; w < 4; ++w) {
        int idx = t + 256*w;
        int ii2 = idx >> 5, jj = idx & 31;
        double v = 0.0;
        if (i0 + ii2 < K)
          v = Sg[(size_t)(r0 + i0 + ii2)*256 + jt*32 + jj];
        Ss[ii2][jj] = v;
      }
      __syncthreads();
      int kmax = (K - i0 < 32) ? (K - i0) : 32;
      for (int ii = 0; ii < kmax; ++ii) {
        double gv = Gs[ii][rl];
        #pragma unroll
        for (int q = 0; q < 8; ++q) acc[q] += Ss[ii][jl + 4*q] * gv;
      }
      __syncthreads();
    }
  }
  if (r < nn) {
    #pragma unroll
    for (int q = 0; q < 8; ++q) {
      int j = jt*32 + jl + 4*q;
      if (j < K) Qn[(size_t)(r0 + j)*256 + r0 + r] = acc[q];
      else if (j < nn) {
        int p = K2 + (j - K);
        Qn[(size_t)(r0 + j)*256 + r0 + r] = Q[(size_t)(r0 + sindxp[p])*256 + r0 + r];
      }
    }
  }
}

// ================= merge phase 3: permute rows back into QT =================
__global__ __launch_bounds__(256) void k_mperm(int n1, const double* __restrict__ QNT,
        const int* __restrict__ META, double* __restrict__ QT) {
  int mrg = blockIdx.x, b = blockIdx.y, t = threadIdx.x;
  int nn = 2*n1, r0 = mrg*nn;
  const int* meta = META + ((b*8 + mrg)*520);
  __shared__ int pf[256];
  if (t < nn) pf[t] = meta[258 + t];
  __syncthreads();
  if (t < nn) {
    for (int f = 0; f < nn; ++f)
      QT[(size_t)b*65536 + (size_t)(r0 + f)*256 + r0 + t] =
        QNT[(size_t)b*65536 + (size_t)(r0 + pf[f])*256 + r0 + t];
  }
}

// ================= back-transform, LDS-tiled: 16 eigvecs/block, emit Vt (f32) directly =================
__global__ __launch_bounds__(256) void k_backxf(const double* __restrict__ A, const double* __restrict__ tau_g,
        const double* __restrict__ QT, float* __restrict__ Vt) {
  int g = blockIdx.x, b = blockIdx.y;
  int t = threadIdx.x;
  int e = t >> 4, l = t & 15;
  __shared__ double zt[16][264];
  __shared__ double vL[256];
  __shared__ double tauL[256];
  const double* Ab = A + (size_t)b*65536;
  const double* Qb = QT + (size_t)b*65536 + (size_t)g*16*256;
  #pragma unroll
  for (int w = 0; w < 16; ++w) {
    int idx = t + 256*w;
    int ee = idx >> 8, rr = idx & 255;
    zt[ee][rr] = Qb[(size_t)ee*256 + rr];
  }
  tauL[t] = tau_g[b*256 + t];
  __syncthreads();
  for (int s = 253; s >= 0; --s) {
    if (t == 0) vL[s+1] = 1.0;
    int rx = s + 2 + t;
    if (rx < 256) vL[rx] = Ab[s*256 + rx];
    __syncthreads();
    double tauv = tauL[s];
    if (tauv != 0.0) {
      double acc = 0.0;
      for (int rr = s + 1 + l; rr < 256; rr += 16) acc += vL[rr]*zt[e][rr];
      acc += __shfl_xor(acc, 1);
      acc += __shfl_xor(acc, 2);
      acc += __shfl_xor(acc, 4);
      acc += __shfl_xor(acc, 8);
      double tw = tauv*acc;
      for (int rr = s + 1 + l; rr < 256; rr += 16) zt[e][rr] -= tw*vL[rr];
    }
    __syncthreads();
  }
  float* vtb = Vt + ((size_t)b*256 + (size_t)g*16)*256;
  #pragma unroll
  for (int w = 0; w < 16; ++w) {
    int idx = t + 256*w;
    int ee = idx >> 8, rr = idx & 255;
    vtb[(size_t)ee*256 + rr] = (float)zt[ee][rr];
  }
}

// ================= x_proj = V x, + x, fused maxpool + noise output =================
__global__ __launch_bounds__(256) void k_xproj(const float* __restrict__ x, const float* __restrict__ Vt,
        float* __restrict__ xp, float* __restrict__ noise_out) {
  int R = blockIdx.x, ct = blockIdx.y, b = blockIdx.z;
  int t = threadIdx.x;
  int cl = t >> 3, l8 = t & 7;
  __shared__ float vsh[32][20];
  __shared__ float xs[16][520];
  const float* xb = x + (size_t)b*256*NPX;
  int s0 = R*512;
  float acc[64];
  #pragma unroll
  for (int p = 0; p < 64; ++p) acc[p] = 0.0f;
  for (int d0 = 0; d0 < 256; d0 += 16) {
    for (int q = t; q < 512; q += 256) {
      int c = q >> 4, dd = q & 15;
      vsh[c][dd] = Vt[((size_t)b*256 + ct*32 + c)*256 + d0 + dd];
    }
    for (int q = t; q < 8192; q += 256) {
      int dd = q >> 9, px = q & 511;
      xs[dd][px] = xb[(size_t)(d0 + dd)*NPX + s0 + px];
    }
    __syncthreads();
    for (int dd = 0; dd < 16; ++dd) {
      float a = vsh[cl][dd];
      const float* xr = &xs[dd][l8];
      #pragma unroll
      for (int p = 0; p < 64; ++p) acc[p] += a*xr[8*p];
    }
    __syncthreads();
  }
  int cg = ct*32 + cl;
  const float* xc = xb + (size_t)cg*NPX + s0;
  float vmax[16];
  #pragma unroll
  for (int j = 0; j < 16; ++j) vmax[j] = -3.0e38f;
  bool isnz = (ct == 0);
  #pragma unroll
  for (int p = 0; p < 64; ++p) {
    int px = l8 + 8*p;
    float val = acc[p] + xc[px];
    vmax[p & 15] = fmaxf(vmax[p & 15], val);
    if (isnz) noise_out[((size_t)b*32 + cl)*NPX + s0 + px] = val;
  }
  #pragma unroll
  for (int j = 0; j < 16; ++j) {
    float v = vmax[j];
    v = fmaxf(v, __shfl_xor(v, 1));
    v = fmaxf(v, __shfl_xor(v, 2));
    vmax[j] = v;
  }
  if ((l8 & 3) == 0) {
    int halfsel = l8 >> 2;
    #pragma unroll
    for (int j = 0; j < 16; ++j)
      xp[((size_t)b*256 + cg)*PPX + R*32 + 2*j + halfsel] = vmax[j];
  }
}

// ================= qkv 1x1 conv (672 needed rows) =================
__global__ __launch_bounds__(256) void k_qkv(const float* __restrict__ xp, const float* __restrict__ wq,
        const float* __restrict__ bq, float* __restrict__ qkvm) {
  int pt = blockIdx.x, ot = blockIdx.y, b = blockIdx.z;
  int t = threadIdx.x;
  int ol = t & 31, pg = t >> 5;
  __shared__ float wsh[32][9];
  __shared__ float xsh[8][260];
  float acc[32];
  #pragma unroll
  for (int j = 0; j < 32; ++j) acc[j] = 0.0f;
  for (int ic0 = 0; ic0 < 256; ic0 += 8) {
    {
      int o = t >> 3, j = t & 7;
      int orow = ot*32 + o;
      int reg = orow/224, rem = orow - reg*224;
      int wrow = 32 + rem + 256*reg;
      wsh[o][j] = wq[(size_t)wrow*256 + ic0 + j];
    }
    for (int q = t; q < 2048; q += 256) {
      int ic = q >> 8, px = q & 255;
      xsh[ic][px] = xp[((size_t)b*256 + ic0 + ic)*PPX + pt*256 + px];
    }
    __syncthreads();
    for (int ic = 0; ic < 8; ++ic) {
      float a = wsh[ol][ic];
      const float* xr = &xsh[ic][pg];
      #pragma unroll
      for (int j = 0; j < 32; ++j) acc[j] += a*xr[8*j];
    }
    __syncthreads();
  }
  int orow = ot*32 + ol;
  int reg = orow/224, rem = orow - reg*224;
  float bv = bq[32 + rem + 256*reg];
  #pragma unroll
  for (int j = 0; j < 32; ++j)
    qkvm[((size_t)b*672 + orow)*PPX + pt*256 + pg + 8*j] = acc[j] + bv;
}

// ================= attention =================
__global__ __launch_bounds__(256) void k_attn(const float* __restrict__ qkvm, const float* __restrict__ emb,
        const float* __restrict__ xp, float* __restrict__ pool) {
  int rt = blockIdx.x, n = blockIdx.y, b = blockIdx.z;
  int t = threadIdx.x;
  int rl = t >> 5, pg = t & 31;
  __shared__ float S[8][1032];
  __shared__ float qsh[8][33];
  __shared__ float kv[4224];
  const float* qb = qkvm + (size_t)b*672*PPX;
  int rg0 = rt*8;
  {
    int rg = rg0 + rl;
    float qv = qb[(size_t)(32*n + (rg >> 5))*PPX + ((rg & 31) << 5) + pg];
    float ev = emb[(((size_t)n*8 + b)*1024 + rg)*32 + pg];
    qsh[rl][pg] = (qv + ev)*0.17677669529663688f;
  }
  __syncthreads();
  const float* kb = qb + (size_t)(224 + 32*n)*PPX;
  for (int p0 = 0; p0 < 1024; p0 += 128) {
    for (int q = t; q < 4096; q += 256) {
      int c = q >> 7, pp = q & 127;
      kv[c*132 + pp] = kb[(size_t)c*PPX + p0 + pp];
    }
    __syncthreads();
    float a0 = 0, a1 = 0, a2 = 0, a3 = 0;
    for (int c = 0; c < 32; ++c) {
      float qv = qsh[rl][c];
      const float* kr = &kv[c*132 + pg];
      a0 += qv*kr[0]; a1 += qv*kr[32]; a2 += qv*kr[64]; a3 += qv*kr[96];
    }
    S[rl][p0 + pg]      = a0;
    S[rl][p0 + pg + 32] = a1;
    S[rl][p0 + pg + 64] = a2;
    S[rl][p0 + pg + 96] = a3;
    __syncthreads();
  }
  float mx = -3.0e38f;
  for (int j = 0; j < 32; ++j) mx = fmaxf(mx, S[rl][pg + 32*j]);
  #pragma unroll
  for (int m = 1; m <= 16; m <<= 1) mx = fmaxf(mx, __shfl_xor(mx, m));
  float sum = 0.0f;
  for (int j = 0; j < 32; ++j) {
    float e = expf(S[rl][pg + 32*j] - mx);
    S[rl][pg + 32*j] = e;
    sum += e;
  }
  #pragma unroll
  for (int m = 1; m <= 16; m <<= 1) sum += __shfl_xor(sum, m);
  float inv = 1.0f/sum;
  for (int j = 0; j < 32; ++j) S[rl][pg + 32*j] *= inv;
  __syncthreads();
  const float* vb = qb + (size_t)(448 + 32*n)*PPX;
  float acc = 0.0f;
  for (int p0 = 0; p0 < 1024; p0 += 128) {
    for (int q = t; q < 4096; q += 256) {
      int pp = q >> 5, c = q & 31;
      int p = p0 + pp;
      kv[pp*33 + c] = vb[(size_t)(p >> 5)*PPX + ((p & 31) << 5) + c];
    }
    __syncthreads();
    for (int pp = 0; pp < 128; ++pp) acc += S[rl][p0 + pp]*kv[pp*33 + pg];
    __syncthreads();
  }
  int rg = rg0 + rl;
  int ch = 32*n + (rg >> 5);
  size_t sp = (size_t)((rg & 31) << 5) + pg;
  pool[((size_t)b*224 + ch)*PPX + sp] = acc + xp[((size_t)b*256 + 32 + ch)*PPX + sp];
}

__global__ void k_owt(const float* __restrict__ ow, float* __restrict__ owt) {
  int t = blockIdx.x*256 + threadIdx.x;
  if (t < 256*224) {
    int oc = t/224, ch = t - oc*224;
    owt[(size_t)ch*256 + oc] = ow[t];
  }
}

// ================= bilinear + sim gating + final conv =================
__global__ __launch_bounds__(256) void k_final(const float* __restrict__ pool, const float* __restrict__ noise,
        const float* __restrict__ sim_w, const float* __restrict__ owt, float* __restrict__ out) {
  int tt = blockIdx.x, b = blockIdx.y;
  int t = threadIdx.x;
  int h = tt >> 3, w0 = (tt & 7)*16;
  __shared__ float xa[224][20];
  __shared__ float nsc[224][20];
  __shared__ float nz[32][20];
  __shared__ float scl[16];
  for (int q = t; q < 512; q += 256) {
    int c = q >> 4, px = q & 15;
    nz[c][px] = noise[((size_t)b*32 + c)*NPX + h*128 + w0 + px];
  }
  float hs = h*0.25f - 0.375f;
  float hf = floorf(hs);
  int h0 = (int)hf;
  float fh = hs - hf;
  int h0c = min(max(h0, 0), 31);
  int h1c = min(max(h0 + 1, 0), 31);
  __syncthreads();
  for (int q = t; q < 3584; q += 256) {
    int c = q >> 4, px = q & 15;
    int w = w0 + px;
    float wsrc = w*0.25f - 0.375f;
    float wf = floorf(wsrc);
    int W0 = (int)wf;
    float fw = wsrc - wf;
    int w0c = min(max(W0, 0), 31);
    int w1c = min(max(W0 + 1, 0), 31);
    const float* pb = pool + ((size_t)b*224 + c)*PPX;
    float v00 = pb[h0c*32 + w0c], v01 = pb[h0c*32 + w1c];
    float v10 = pb[h1c*32 + w0c], v11 = pb[h1c*32 + w1c];
    xa[c][px] = (1.0f - fh)*((1.0f - fw)*v00 + fw*v01) + fh*((1.0f - fw)*v10 + fw*v11);
    float np = 0.0f;
    #pragma unroll
    for (int j = 0; j < 32; ++j) np += sim_w[c*32 + j]*nz[j][px];
    nsc[c][px] = np;
  }
  __syncthreads();
  {
    int px = t >> 4, kk = t & 15;
    float s1 = 0, s2 = 0, s3 = 0;
    for (int c = kk; c < 224; c += 16) {
      float a = xa[c][px], p = nsc[c][px];
      s1 += a*a; s2 += p*p; s3 += a*p;
    }
    #pragma unroll
    for (int m = 1; m <= 8; m <<= 1) {
      s1 += __shfl_xor(s1, m);
      s2 += __shfl_xor(s2, m);
      s3 += __shfl_xor(s3, m);
    }
    if (kk == 0) {
      float n1 = fmaxf(sqrtf(s1), 1e-12f);
      float n2 = fmaxf(sqrtf(s2), 1e-12f);
      float sim = (s3/(n1*n2) + 1.0f)*0.5f;
      scl[px] = 1.0f - sim;
    }
  }
  __syncthreads();
  {
    float accp[16];
    #pragma unroll
    for (int px = 0; px < 16; ++px) accp[px] = 0.0f;
    for (int c = 0; c < 224; ++c) {
      float wv = owt[(size_t)c*256 + t];
      #pragma unroll
      for (int px = 0; px < 16; ++px) accp[px] += wv*xa[c][px];
    }
    size_t obase = ((size_t)b*256 + t)*NPX + (size_t)h*128 + w0;
    #pragma unroll
    for (int px = 0; px < 16; ++px) out[obase + px] = accp[px]*scl[px];
  }
  if (b == 0 && tt == 0 && t == 0) out[(size_t)33554432] = 8.0f;   // AVG_K
}

extern "C" void kernel_launch(void* const* d_in, const int* in_sizes, int n_in,
                              void* d_out, int out_size, void* d_ws, size_t ws_size,
                              hipStream_t stream) {
  (void)in_sizes; (void)n_in; (void)out_size; (void)ws_size;
  const float* x     = (const float*)d_in[0];
  const float* qkv_w = (const float*)d_in[1];
  const float* qkv_b = (const float*)d_in[2];
  const float* emb   = (const float*)d_in[3];
  const float* sim_w = (const float*)d_in[4];
  const float* out_w = (const float*)d_in[5];
  float* out = (float*)d_out;
  char* ws = (char*)d_ws;
  double* gram = (double*)(ws + OFF_GRAM);
  double* A    = (double*)(ws + OFF_A);
  double* QT   = (double*)(ws + OFF_QT);
  double* SG   = (double*)(ws + OFF_SG);
  double* QNT  = (double*)(ws + OFF_QN);
  double* d_a  = (double*)(ws + OFF_D);
  double* e_a  = (double*)(ws + OFF_E);
  double* tau_a= (double*)(ws + OFF_TAU);
  double* DW   = (double*)(ws + OFF_DW);
  int*    META = (int*)   (ws + OFF_META);
  float*  Vt   = (float*) (ws + OFF_VT);
  float*  xp   = (float*) (ws + OFF_XP);
  float*  qkvm = (float*) (ws + OFF_QKV);
  float*  pool = (float*) (ws + OFF_POOL);
  float*  owt  = (float*) (ws + OFF_OWT);
  float*  noise_out = out + 33554433;

  k_gram   <<<dim3(8,8,8),   256, 0, stream>>>(x, gram);
  k_tridiag<<<dim3(8),       256, 0, stream>>>(gram, A, d_a, e_a, tau_a);
  k_zeroq  <<<dim3(512),     256, 0, stream>>>(QT);
  k_leaves <<<dim3(8),       64,  0, stream>>>(d_a, e_a, QT, DW);
  // merge levels: n1 = 16, 32, 64, 128; nmrg = 8, 4, 2, 1
  {
    const int n1s[4]   = {16, 32, 64, 128};
    const int nmrgs[4] = {8, 4, 2, 1};
    for (int lv = 0; lv < 4; ++lv) {
      int n1 = n1s[lv], nmrg = nmrgs[lv], nn = 2*n1;
      k_mscan<<<dim3(nmrg, 8), 256, 0, stream>>>(n1, e_a, QT, DW, SG, META);
      k_mgemm<<<dim3(nn/32, (nn + 63)/64, nmrg*8), 256, 0, stream>>>(n1, nmrg, QT, SG, META, QNT);
      k_mperm<<<dim3(nmrg, 8), 256, 0, stream>>>(n1, QNT, META, QT);
    }
  }
  k_backxf <<<dim3(16,8),    256, 0, stream>>>(A, tau_a, QT, Vt);
  k_xproj  <<<dim3(32,8,8),  256, 0, stream>>>(x, Vt, xp, noise_out);
  k_qkv    <<<dim3(4,21,8),  256, 0, stream>>>(xp, qkv_w, qkv_b, qkvm);
  k_attn   <<<dim3(128,7,8), 256, 0, stream>>>(qkvm, emb, xp, pool);
  k_owt    <<<dim3(224),     256, 0, stream>>>(out_w, owt);
  k_final  <<<dim3(1024,8),  256, 0, stream>>>(pool, noise_out, sim_w, owt, out);
}

// Round 8
// 10391.545 us; speedup vs baseline: 2.2950x; 1.2455x over previous
//
#include <hip/hip_runtime.h>
#include <math.h>

#define NB  8
#define NPX 16384   // 128*128
#define PPX 1024    // 32*32

// f32 LAPACK machine constants (SLAMCH) used for branch tolerances
#define EPS32   5.9604644775390625e-8   // 2^-24 (slamch 'E')
#define EPS232  (EPS32*EPS32)
#define SAFMIN32 1.1754943508222875e-38

// ---------------- workspace layout (bytes), phase-aliased ----------------
static constexpr size_t OFF_VT   = 0;                    // f32 [8][256][256] 2MB (lives across phases)
static constexpr size_t U        = 0x200000;
static constexpr size_t OFF_GRAM = U;                    // f64 [8][256][256] 4MB
static constexpr size_t OFF_A    = U + 0x400000;         // f64 [8][256][256] 4MB reflectors
static constexpr size_t OFF_QT   = U + 0x800000;         // f64 [8][256][256] 4MB QT[col][row] (tridiag eigvecs, transposed)
static constexpr size_t OFF_SG   = U + 0xC00000;         // f64 [8][256][256] 4MB S scratch
static constexpr size_t OFF_QN   = U + 0x1000000;        // f64 [8][256][256] 4MB QNT scratch
static constexpr size_t OFF_D    = U + 0x1400000;        // f64 [8][256]
static constexpr size_t OFF_E    = U + 0x1404000;        // f64 [8][256]
static constexpr size_t OFF_TAU  = U + 0x1408000;        // f64 [8][256]
static constexpr size_t OFF_DW   = U + 0x140C000;        // f64 [8][256] working eigenvalues
static constexpr size_t OFF_META = U + 0x1410000;        // int [8][8][520]  K,K2,indxp[256],permf[256]
// phase2 aliases (phase1 dead in order: GRAM after tridiag, A/QT after backxf, SG/QN/META after merges):
static constexpr size_t OFF_XP   = U;                    // f32 [8][256][1024] 8MB
static constexpr size_t OFF_QKV  = U + 0x800000;         // f32 [8][672][1024] 21MB
static constexpr size_t OFF_POOL = U + 0x1D00000;        // f32 [8][224][1024] 7MB
static constexpr size_t OFF_OWT  = U + 0x2400000;        // f32 [224][256]

// ================= gram = X X^T (f64 accumulate) =================
__global__ __launch_bounds__(256) void k_gram(const float* __restrict__ x, double* __restrict__ gram) {
  int jt = blockIdx.x, it = blockIdx.y, b = blockIdx.z;
  __shared__ float xi[32][129], xj[32][129];
  const float* xb = x + (size_t)b*256*NPX;
  int t = threadIdx.x;
  int ci = t & 31, cjg = t >> 5;
  double acc[4] = {0.0,0.0,0.0,0.0};
  for (int n0 = 0; n0 < NPX; n0 += 128) {
    for (int q = 0; q < 16; ++q) {
      int idx = t + q*256;
      int r = idx >> 7, cc = idx & 127;
      xi[r][cc] = xb[(size_t)(it*32 + r)*NPX + n0 + cc];
      xj[r][cc] = xb[(size_t)(jt*32 + r)*NPX + n0 + cc];
    }
    __syncthreads();
    for (int p = 0; p < 128; ++p) {
      double a = (double)xi[ci][p];
      #pragma unroll
      for (int k = 0; k < 4; ++k) acc[k] += a * (double)xj[cjg + 8*k][p];
    }
    __syncthreads();
  }
  #pragma unroll
  for (int k = 0; k < 4; ++k)
    gram[((size_t)b*256 + it*32 + ci)*256 + jt*32 + cjg + 8*k] = acc[k];
}

__device__ __forceinline__ double blkSum16(double v, double* tmp, int t, int nw) {
  #pragma unroll
  for (int m = 1; m <= 32; m <<= 1) v += __shfl_xor(v, m);
  __syncthreads();
  if ((t & 63) == 0) tmp[t >> 6] = v;
  __syncthreads();
  double s = 0.0;
  for (int w = 0; w < nw; ++w) s += tmp[w];
  return s;
}

// ================= Householder tridiagonalization (dsytd2 'L', f64, 1024 threads) =================
__global__ __launch_bounds__(1024) void k_tridiag(const double* __restrict__ gram, double* __restrict__ A,
        double* __restrict__ d_g, double* __restrict__ e_g, double* __restrict__ tau_g) {
  int b = blockIdx.x, t = threadIdx.x;
  int g = t >> 8, c = t & 255;
  const double* gb = gram + (size_t)b*65536;
  double* Ab = A + (size_t)b*65536;
  __shared__ double vL[256], wL[256];
  __shared__ double wpart[4][256];
  __shared__ double tmp[16];
  for (int q = g; q < 256; q += 4) Ab[q*256 + c] = gb[q*256 + c];
  __syncthreads();
  for (int i = 0; i < 255; ++i) {
    // ||x||^2 of A[i][i+2..255] (row i by symmetry; only low threads have rx<256)
    double part = 0.0;
    int rx = i + 2 + t;
    if (rx < 256) { double v = Ab[i*256 + rx]; part = v*v; }
    double xn2 = blkSum16(part, tmp, t, 16);
    double alpha = Ab[i*256 + i + 1];
    double beta, tauv, scale;
    if (xn2 == 0.0) { beta = alpha; tauv = 0.0; scale = 0.0; }
    else {
      beta  = -copysign(sqrt(alpha*alpha + xn2), alpha);   // dlarfg
      tauv  = (beta - alpha)/beta;
      scale = 1.0/(alpha - beta);
    }
    if (t == 0) { e_g[b*256 + i] = beta; tau_g[b*256 + i] = tauv; vL[i+1] = 1.0; }
    if (rx < 256) {
      double v = Ab[i*256 + rx] * scale;
      vL[rx] = v;
      Ab[i*256 + rx] = v;                 // store v in row i for back-transform
    }
    __syncthreads();
    if (tauv != 0.0) {                    // uniform branch
      int cc = i + 1 + c;
      double w = 0.0;
      if (cc < 256) {
        for (int r = i + 1 + g; r < 256; r += 4) w += Ab[r*256 + cc] * vL[r];
      }
      wpart[g][c] = w;
      __syncthreads();
      double wfull = 0.0, part2 = 0.0;
      if (g == 0 && cc < 256) {
        wfull = (wpart[0][c] + wpart[1][c] + wpart[2][c] + wpart[3][c]) * tauv;
        part2 = vL[cc] * wfull;
      }
      double dot = blkSum16(part2, tmp, t, 16);
      double coef = -0.5*tauv*dot;
      if (g == 0 && cc < 256) wL[cc] = wfull + coef*vL[cc];
      __syncthreads();
      if (cc < 256) {
        double vc = vL[cc], wc = wL[cc];
        for (int r = i + 1 + g; r < 256; r += 4)
          Ab[r*256 + cc] = Ab[r*256 + cc] - vL[r]*wc - wL[r]*vc;
      }
      __syncthreads();
    } else {
      __syncthreads();
    }
  }
  if (t < 256) d_g[b*256 + t] = Ab[t*256 + t];
  if (t == 0) e_g[b*256 + 255] = 0.0;
}

// ================= LAPACK helpers =================
__device__ __forceinline__ void dlartg_(double f, double g, double& c, double& s, double& r) {
  if (g == 0.0) { c = 1.0; s = 0.0; r = f; }
  else if (f == 0.0) { c = 0.0; s = (g > 0.0) ? 1.0 : -1.0; r = fabs(g); }
  else {
    double d = sqrt(f*f + g*g);
    r = (f >= 0.0) ? d : -d;
    c = f / r;
    s = g / r;
  }
}

__device__ void dlaev2_(double a, double b, double cc, double& rt1, double& rt2, double& cs1, double& sn1) {
  double sm = a + cc, df = a - cc;
  double adf = fabs(df), tb = b + b, ab = fabs(tb);
  double acmx, acmn;
  if (fabs(a) > fabs(cc)) { acmx = a; acmn = cc; } else { acmx = cc; acmn = a; }
  double rt;
  if (adf > ab)      rt = adf*sqrt(1.0 + (ab/adf)*(ab/adf));
  else if (adf < ab) rt = ab*sqrt(1.0 + (adf/ab)*(adf/ab));
  else               rt = ab*sqrt(2.0);
  int sgn1;
  if (sm < 0.0)      { rt1 = 0.5*(sm - rt); sgn1 = -1; rt2 = (acmx/rt1)*acmn - (b/rt1)*b; }
  else if (sm > 0.0) { rt1 = 0.5*(sm + rt); sgn1 = 1;  rt2 = (acmx/rt1)*acmn - (b/rt1)*b; }
  else               { rt1 = 0.5*rt; rt2 = -0.5*rt; sgn1 = 1; }
  double cs; int sgn2;
  if (df >= 0.0) { cs = df + rt; sgn2 = 1; } else { cs = df - rt; sgn2 = -1; }
  double acs = fabs(cs);
  if (acs > ab) {
    double ct = -tb/cs;
    sn1 = 1.0/sqrt(1.0 + ct*ct);
    cs1 = ct*sn1;
  } else {
    if (ab == 0.0) { cs1 = 1.0; sn1 = 0.0; }
    else {
      double tn = -cs/tb;
      cs1 = 1.0/sqrt(1.0 + tn*tn);
      sn1 = tn*cs1;
    }
  }
  if (sgn1 == sgn2) { double tn = cs1; cs1 = -sn1; sn1 = tn; }
}

// faithful dsteqr('I') on an n<=16 block, f64 arithmetic with f32 tolerances
__device__ void steqr_leaf(int n, double* d, double* e, double* q, int ldq) {
  const double eps = EPS32, eps2 = EPS232, safmin = SAFMIN32;
  int nmaxit = n*30, jtot = 0;
  int l1 = 0;
  while (l1 < n) {
    if (l1 > 0) e[l1-1] = 0.0;
    int m;
    for (m = l1; m < n-1; ++m) {
      double tst = fabs(e[m]);
      if (tst == 0.0) break;
      if (tst <= (sqrt(fabs(d[m]))*sqrt(fabs(d[m+1])))*eps) { e[m] = 0.0; break; }
    }
    int l = l1, lend = m;
    l1 = m + 1;
    if (lend == l) continue;
    if (fabs(d[lend]) < fabs(d[l])) { int tsw = l; l = lend; lend = tsw; }
    if (lend > l) {
      while (true) {
        int mm;
        for (mm = l; mm < lend; ++mm) {
          double tst = e[mm]*e[mm];
          if (tst <= (eps2*fabs(d[mm]))*fabs(d[mm+1]) + safmin) break;
        }
        if (mm < lend) e[mm] = 0.0;
        double p = d[l];
        if (mm == l) { l = l + 1; if (l > lend) break; continue; }
        if (mm == l+1) {
          double rt1, rt2, c, s;
          dlaev2_(d[l], e[l], d[l+1], rt1, rt2, c, s);
          for (int i = 0; i < n; ++i) {
            double t1 = q[i*ldq + l+1], t0 = q[i*ldq + l];
            q[i*ldq + l+1] = c*t1 - s*t0;
            q[i*ldq + l]   = s*t1 + c*t0;
          }
          d[l] = rt1; d[l+1] = rt2; e[l] = 0.0;
          l += 2; if (l > lend) break; continue;
        }
        if (jtot == nmaxit) break;
        jtot++;
        double g = (d[l+1] - p)/(2.0*e[l]);
        double r = sqrt(g*g + 1.0);
        g = d[mm] - p + e[l]/(g + copysign(r, g));
        double s = 1.0, c = 1.0; p = 0.0;
        double csv[16], snv[16];
        for (int i = mm-1; i >= l; --i) {
          double f = s*e[i], bb = c*e[i];
          dlartg_(g, f, c, s, r);
          if (i != mm-1) e[i+1] = r;
          g = d[i+1] - p;
          r = (d[i] - g)*s + 2.0*c*bb;
          p = s*r;
          d[i+1] = g + p;
          g = c*r - bb;
          csv[i] = c; snv[i] = -s;
        }
        for (int i = mm-1; i >= l; --i) {
          double cc2 = csv[i], ss2 = snv[i];
          for (int k = 0; k < n; ++k) {
            double t1 = q[k*ldq + i+1], t0 = q[k*ldq + i];
            q[k*ldq + i+1] = cc2*t1 - ss2*t0;
            q[k*ldq + i]   = ss2*t1 + cc2*t0;
          }
        }
        d[l] -= p; e[l] = g;
      }
    } else {
      while (true) {
        int mm;
        for (mm = l; mm > lend; --mm) {
          double tst = e[mm-1]*e[mm-1];
          if (tst <= (eps2*fabs(d[mm]))*fabs(d[mm-1]) + safmin) break;
        }
        if (mm > lend) e[mm-1] = 0.0;
        double p = d[l];
        if (mm == l) { l = l - 1; if (l < lend) break; continue; }
        if (mm == l-1) {
          double rt1, rt2, c, s;
          dlaev2_(d[l-1], e[l-1], d[l], rt1, rt2, c, s);
          for (int i = 0; i < n; ++i) {
            double t1 = q[i*ldq + l], t0 = q[i*ldq + l-1];
            q[i*ldq + l]   = c*t1 - s*t0;
            q[i*ldq + l-1] = s*t1 + c*t0;
          }
          d[l-1] = rt1; d[l] = rt2; e[l-1] = 0.0;
          l -= 2; if (l < lend) break; continue;
        }
        if (jtot == nmaxit) break;
        jtot++;
        double g = (d[l-1] - p)/(2.0*e[l-1]);
        double r = sqrt(g*g + 1.0);
        g = d[mm] - p + e[l-1]/(g + copysign(r, g));
        double s = 1.0, c = 1.0; p = 0.0;
        double csv[16], snv[16];
        for (int i = mm; i <= l-1; ++i) {
          double f = s*e[i], bb = c*e[i];
          dlartg_(g, f, c, s, r);
          if (i != mm) e[i-1] = r;
          g = d[i] - p;
          r = (d[i+1] - g)*s + 2.0*c*bb;
          p = s*r;
          d[i] = g + p;
          g = c*r - bb;
          csv[i] = c; snv[i] = s;
        }
        for (int i = mm; i <= l-1; ++i) {
          double cc2 = csv[i], ss2 = snv[i];
          for (int k = 0; k < n; ++k) {
            double t1 = q[k*ldq + i+1], t0 = q[k*ldq + i];
            q[k*ldq + i+1] = cc2*t1 - ss2*t0;
            q[k*ldq + i]   = ss2*t1 + cc2*t0;
          }
        }
        d[l] -= p; e[l-1] = g;
      }
    }
  }
  for (int ii = 1; ii < n; ++ii) {
    int k = ii - 1; double p = d[k];
    for (int j = ii; j < n; ++j) if (d[j] < p) { k = j; p = d[j]; }
    if (k != ii-1) {
      d[k] = d[ii-1]; d[ii-1] = p;
      for (int r = 0; r < n; ++r) { double tq = q[r*ldq + ii-1]; q[r*ldq + ii-1] = q[r*ldq + k]; q[r*ldq + k] = tq; }
    }
  }
}

__global__ __launch_bounds__(256) void k_zeroq(double* __restrict__ QT) {
  size_t i = (size_t)blockIdx.x*256 + threadIdx.x;
  size_t total = (size_t)NB*65536;
  for (; i < total; i += (size_t)gridDim.x*256) QT[i] = 0.0;
}

// ================= leaves: tears + 16x ssteqr(16), write TRANSPOSED (QT[eigvec][component]) =================
__global__ __launch_bounds__(64) void k_leaves(const double* __restrict__ d_g, const double* __restrict__ e_g,
        double* __restrict__ QT, double* __restrict__ DW) {
  int b = blockIdx.x, t = threadIdx.x;
  __shared__ double dL[256], eL[256];
  __shared__ double ql[16*272];   // 16 leaves x [16][17]
  for (int i = t; i < 256; i += 64) { dL[i] = d_g[b*256 + i]; eL[i] = e_g[b*256 + i]; }
  __syncthreads();
  if (t == 0) {
    for (int cut = 16; cut < 256; cut += 16) {
      double a = fabs(eL[cut-1]);
      dL[cut-1] -= a; dL[cut] -= a;
    }
  }
  __syncthreads();
  if (t < 16) {
    double* q = &ql[t*272];
    for (int i = 0; i < 16; ++i)
      for (int j = 0; j < 16; ++j) q[i*17 + j] = (i == j) ? 1.0 : 0.0;
    steqr_leaf(16, dL + 16*t, eL + 16*t, q, 17);
  }
  __syncthreads();
  for (int idx = t; idx < 4096; idx += 64) {
    int lf = idx >> 8, i = (idx >> 4) & 15, j = idx & 15;
    QT[(size_t)b*65536 + (size_t)(lf*16 + j)*256 + lf*16 + i] = ql[lf*272 + i*17 + j];
  }
  for (int i = t; i < 256; i += 64) DW[b*256 + i] = dL[i];
}

// ================= merge phase 1: scan + rotations + secular + S (dlaed1/2/3 faithful) =================
__global__ __launch_bounds__(256) void k_mscan(int n1, const double* __restrict__ e_g,
        double* __restrict__ QT, double* __restrict__ DW, double* __restrict__ SG, int* __restrict__ META) {
  int mrg = blockIdx.x, b = blockIdx.y, t = threadIdx.x;
  int nn = 2*n1, r0 = mrg*nn;
  double* Q = QT + (size_t)b*65536;
  double* Sg = SG + (size_t)b*65536;
  int* meta = META + ((b*8 + mrg)*520);
  __shared__ double dloc[256], zloc[256], dlam[256], wv[256], w2[256], tauv[256], zh[256], dfin[256];
  __shared__ int indx[256], indxp[256], permf[256];
  __shared__ double rotc[256], rots[256];
  __shared__ short rotp[256], rotq[256];
  __shared__ int KK[3];
  __shared__ double sc[2];
  double rho_raw = e_g[b*256 + r0 + n1 - 1];
  if (t < nn) {
    dloc[t] = DW[b*256 + r0 + t];
    double zv = Q[(size_t)(r0 + t)*256 + r0 + ((t < n1) ? (n1 - 1) : n1)];
    if (t >= n1 && rho_raw < 0.0) zv = -zv;      // dlaed2
    zloc[t] = zv * 0.70710678118654752440;
  }
  __syncthreads();
  if (t == 0) {
    int i = 0, jj = n1, pos = 0;
    while (i < n1 && jj < nn) { if (dloc[i] <= dloc[jj]) indx[pos++] = i++; else indx[pos++] = jj++; }
    while (i < n1) indx[pos++] = i++;
    while (jj < nn) indx[pos++] = jj++;
    double maxd = 0.0, maxz = 0.0;
    for (int q2 = 0; q2 < nn; ++q2) { maxd = fmax(maxd, fabs(dloc[q2])); maxz = fmax(maxz, fabs(zloc[q2])); }
    double rho = fabs(2.0*rho_raw);
    double tol = 8.0*EPS32*fmax(maxd, maxz);
    int K = 0, K2 = nn, nrot = 0, pj = -1, j = 0;
    for (; j < nn; ++j) {
      int nj = indx[j];
      if (rho*fabs(zloc[nj]) <= tol) { K2--; indxp[K2] = nj; }
      else { pj = nj; break; }
    }
    if (pj >= 0) {
      for (++j; j < nn; ++j) {
        int nj = indx[j];
        if (rho*fabs(zloc[nj]) <= tol) { K2--; indxp[K2] = nj; }
        else {
          double s = zloc[pj], c = zloc[nj];
          double tau = sqrt(c*c + s*s);
          double tdf = dloc[nj] - dloc[pj];
          c /= tau; s = -s/tau;
          if (fabs(tdf*c*s) <= tol) {
            zloc[nj] = tau; zloc[pj] = 0.0;
            rotp[nrot] = (short)pj; rotq[nrot] = (short)nj; rotc[nrot] = c; rots[nrot] = s; nrot++;
            double tt2 = dloc[pj]*c*c + dloc[nj]*s*s;
            dloc[nj] = dloc[pj]*s*s + dloc[nj]*c*c;
            dloc[pj] = tt2;
            K2--;
            int ii2 = 1;
            while (K2 + ii2 <= nn - 1 && dloc[pj] < dloc[indxp[K2 + ii2]]) { indxp[K2+ii2-1] = indxp[K2+ii2]; ii2++; }
            indxp[K2+ii2-1] = pj;
            pj = nj;
          } else {
            dlam[K] = dloc[pj]; wv[K] = zloc[pj]; indxp[K] = pj; K++;
            pj = nj;
          }
        }
      }
      dlam[K] = dloc[pj]; wv[K] = zloc[pj]; indxp[K] = pj; K++;
    }
    double sumw2 = 0.0;
    for (int q2 = 0; q2 < K; ++q2) sumw2 += wv[q2]*wv[q2];
    KK[0] = K; KK[1] = K2; KK[2] = nrot; sc[0] = rho; sc[1] = sumw2;
  }
  __syncthreads();
  int K = KK[0], K2 = KK[1], nrot = KK[2];
  double rho = sc[0], sumw2 = sc[1];
  if (t < nn) {
    for (int k = 0; k < nrot; ++k) {
      int p = rotp[k], q = rotq[k];
      double c = rotc[k], s = rots[k];
      size_t ip = (size_t)(r0 + p)*256 + r0 + t;
      size_t iq = (size_t)(r0 + q)*256 + r0 + t;
      double xq = Q[ip], yq = Q[iq];
      Q[ip] = c*xq + s*yq;
      Q[iq] = c*yq - s*xq;
    }
  }
  if (t < K) w2[t] = rho*wv[t]*wv[t];
  __syncthreads();
  if (t < K) {
    double dj = dlam[t];
    double hi0 = (t < K-1) ? (dlam[t+1] - dj) : rho*sumw2;
    double lo = 0.0, hi = hi0;
    for (int it = 0; it < 64; ++it) {
      double mid = 0.5*(lo + hi);
      double f = 1.0;
      for (int j2 = 0; j2 < K; ++j2) f += w2[j2]/((dlam[j2] - dj) - mid);
      if (f < 0.0) lo = mid; else hi = mid;
    }
    double tl = 0.5*(lo + hi);
    if (tl <= 0.0) tl = hi0*1e-300;
    tauv[t] = tl;
  }
  __syncthreads();
  if (t < K) {
    double dt2 = dlam[t], p = tauv[t];
    for (int i = 0; i < K; ++i) { if (i == t) continue; double del = dlam[i] - dt2; p *= (del + tauv[i])/del; }
    zh[t] = copysign(sqrt(fabs(p)), wv[t]);
  }
  __syncthreads();
  if (t < K) {
    double dj = dlam[t], tj = tauv[t];
    double nrm = 0.0;
    for (int i = 0; i < K; ++i) { double sij = zh[i]/((dlam[i] - dj) - tj); nrm += sij*sij; }
    double inv = 1.0/sqrt(nrm);
    for (int i = 0; i < K; ++i) Sg[(size_t)(r0 + i)*256 + t] = (zh[i]/((dlam[i] - dj) - tj))*inv;
  }
  __syncthreads();
  if (t == 0) {
    int i = 0, p = nn - 1, f = 0;
    while (f < nn) {
      bool takesec;
      if (i < K && p >= K2) takesec = ((dlam[i] + tauv[i]) <= dloc[indxp[p]]);
      else takesec = (i < K);
      if (takesec) { dfin[f] = dlam[i] + tauv[i]; permf[f] = i; i++; }
      else         { dfin[f] = dloc[indxp[p]];    permf[f] = K + (p - K2); p--; }
      f++;
    }
    for (f = 0; f < nn; ++f) DW[b*256 + r0 + f] = dfin[f];
    meta[0] = K; meta[1] = K2;
  }
  __syncthreads();
  if (t < nn) { meta[2 + t] = indxp[t]; meta[258 + t] = permf[t]; }
}

// ================= merge phase 2: QNT[j][r] = sum_i S[i][j] * QT[indxp[i]][r] (LDS-tiled) + deflated copy =================
__global__ __launch_bounds__(256) void k_mgemm(int n1, int nmrg, const double* __restrict__ QT,
        const double* __restrict__ SG, const int* __restrict__ META, double* __restrict__ QNT) {
  int nn = 2*n1;
  int jt = blockIdx.x, rt = blockIdx.y;
  int z = blockIdx.z;
  int mrg = z % nmrg, b = z / nmrg;
  int r0 = mrg*nn;
  int t = threadIdx.x;
  const int* meta = META + ((b*8 + mrg)*520);
  __shared__ int sindxp[256];
  __shared__ double Gs[32][66];
  __shared__ double Ss[32][33];
  const double* Q = QT + (size_t)b*65536;
  const double* Sg = SG + (size_t)b*65536;
  double* Qn = QNT + (size_t)b*65536;
  int K = meta[0], K2 = meta[1];
  if (t < nn) sindxp[t] = meta[2 + t];
  __syncthreads();
  int jl = t >> 6, rl = t & 63;
  int r = rt*64 + rl;
  double acc[8];
  #pragma unroll
  for (int q = 0; q < 8; ++q) acc[q] = 0.0;
  if (jt*32 < K) {
    for (int i0 = 0; i0 < K; i0 += 32) {
      #pragma unroll
      for (int w = 0; w < 8; ++w) {
        int idx = t + 256*w;
        int ii = idx >> 6, rr = idx & 63;
        double v = 0.0;
        if (i0 + ii < K && rt*64 + rr < nn)
          v = Q[(size_t)(r0 + sindxp[i0 + ii])*256 + r0 + rt*64 + rr];
        Gs[ii][rr] = v;
      }
      #pragma unroll
      for (int w = 0; w < 4; ++w) {
        int idx = t + 256*w;
        int ii2 = idx >> 5, jj = idx & 31;
        double v = 0.0;
        if (i0 + ii2 < K)
          v = Sg[(size_t)(r0 + i0 + ii2)*256 + jt*32 + jj];
        Ss[ii2][jj] = v;
      }
      __syncthreads();
      int kmax = (K - i0 < 32) ? (K - i0) : 32;
      for (int ii = 0; ii < kmax; ++ii) {
        double gv = Gs[ii][rl];
        #pragma unroll
        for (int q = 0; q < 8; ++q) acc[q] += Ss[ii][jl + 4*q] * gv;
      }
      __syncthreads();
    }
  }
  if (r < nn) {
    #pragma unroll
    for (int q = 0; q < 8; ++q) {
      int j = jt*32 + jl + 4*q;
      if (j < K) Qn[(size_t)(r0 + j)*256 + r0 + r] = acc[q];
      else if (j < nn) {
        int p = K2 + (j - K);
        Qn[(size_t)(r0 + j)*256 + r0 + r] = Q[(size_t)(r0 + sindxp[p])*256 + r0 + r];
      }
    }
  }
}

// ================= merge phase 3: permute rows back into QT =================
__global__ __launch_bounds__(256) void k_mperm(int n1, const double* __restrict__ QNT,
        const int* __restrict__ META, double* __restrict__ QT) {
  int mrg = blockIdx.x, b = blockIdx.y, t = threadIdx.x;
  int nn = 2*n1, r0 = mrg*nn;
  const int* meta = META + ((b*8 + mrg)*520);
  __shared__ int pf[256];
  if (t < nn) pf[t] = meta[258 + t];
  __syncthreads();
  if (t < nn) {
    for (int f = 0; f < nn; ++f)
      QT[(size_t)b*65536 + (size_t)(r0 + f)*256 + r0 + t] =
        QNT[(size_t)b*65536 + (size_t)(r0 + pf[f])*256 + r0 + t];
  }
}

// ================= back-transform, LDS-tiled: 16 eigvecs/block, emit Vt (f32) directly =================
__global__ __launch_bounds__(256) void k_backxf(const double* __restrict__ A, const double* __restrict__ tau_g,
        const double* __restrict__ QT, float* __restrict__ Vt) {
  int g = blockIdx.x, b = blockIdx.y;
  int t = threadIdx.x;
  int e = t >> 4, l = t & 15;
  __shared__ double zt[16][264];
  __shared__ double vL[256];
  __shared__ double tauL[256];
  const double* Ab = A + (size_t)b*65536;
  const double* Qb = QT + (size_t)b*65536 + (size_t)g*16*256;
  #pragma unroll
  for (int w = 0; w < 16; ++w) {
    int idx = t + 256*w;
    int ee = idx >> 8, rr = idx & 255;
    zt[ee][rr] = Qb[(size_t)ee*256 + rr];
  }
  tauL[t] = tau_g[b*256 + t];
  __syncthreads();
  for (int s = 253; s >= 0; --s) {
    if (t == 0) vL[s+1] = 1.0;
    int rx = s + 2 + t;
    if (rx < 256) vL[rx] = Ab[s*256 + rx];
    __syncthreads();
    double tauv = tauL[s];
    if (tauv != 0.0) {
      double acc = 0.0;
      for (int rr = s + 1 + l; rr < 256; rr += 16) acc += vL[rr]*zt[e][rr];
      acc += __shfl_xor(acc, 1);
      acc += __shfl_xor(acc, 2);
      acc += __shfl_xor(acc, 4);
      acc += __shfl_xor(acc, 8);
      double tw = tauv*acc;
      for (int rr = s + 1 + l; rr < 256; rr += 16) zt[e][rr] -= tw*vL[rr];
    }
    __syncthreads();
  }
  float* vtb = Vt + ((size_t)b*256 + (size_t)g*16)*256;
  #pragma unroll
  for (int w = 0; w < 16; ++w) {
    int idx = t + 256*w;
    int ee = idx >> 8, rr = idx & 255;
    vtb[(size_t)ee*256 + rr] = (float)zt[ee][rr];
  }
}

// ================= x_proj = V x, + x, fused maxpool + noise output =================
__global__ __launch_bounds__(256) void k_xproj(const float* __restrict__ x, const float* __restrict__ Vt,
        float* __restrict__ xp, float* __restrict__ noise_out) {
  int R = blockIdx.x, ct = blockIdx.y, b = blockIdx.z;
  int t = threadIdx.x;
  int cl = t >> 3, l8 = t & 7;
  __shared__ float vsh[32][20];
  __shared__ float xs[16][520];
  const float* xb = x + (size_t)b*256*NPX;
  int s0 = R*512;
  float acc[64];
  #pragma unroll
  for (int p = 0; p < 64; ++p) acc[p] = 0.0f;
  for (int d0 = 0; d0 < 256; d0 += 16) {
    for (int q = t; q < 512; q += 256) {
      int c = q >> 4, dd = q & 15;
      vsh[c][dd] = Vt[((size_t)b*256 + ct*32 + c)*256 + d0 + dd];
    }
    for (int q = t; q < 8192; q += 256) {
      int dd = q >> 9, px = q & 511;
      xs[dd][px] = xb[(size_t)(d0 + dd)*NPX + s0 + px];
    }
    __syncthreads();
    for (int dd = 0; dd < 16; ++dd) {
      float a = vsh[cl][dd];
      const float* xr = &xs[dd][l8];
      #pragma unroll
      for (int p = 0; p < 64; ++p) acc[p] += a*xr[8*p];
    }
    __syncthreads();
  }
  int cg = ct*32 + cl;
  const float* xc = xb + (size_t)cg*NPX + s0;
  float vmax[16];
  #pragma unroll
  for (int j = 0; j < 16; ++j) vmax[j] = -3.0e38f;
  bool isnz = (ct == 0);
  #pragma unroll
  for (int p = 0; p < 64; ++p) {
    int px = l8 + 8*p;
    float val = acc[p] + xc[px];
    vmax[p & 15] = fmaxf(vmax[p & 15], val);
    if (isnz) noise_out[((size_t)b*32 + cl)*NPX + s0 + px] = val;
  }
  #pragma unroll
  for (int j = 0; j < 16; ++j) {
    float v = vmax[j];
    v = fmaxf(v, __shfl_xor(v, 1));
    v = fmaxf(v, __shfl_xor(v, 2));
    vmax[j] = v;
  }
  if ((l8 & 3) == 0) {
    int halfsel = l8 >> 2;
    #pragma unroll
    for (int j = 0; j < 16; ++j)
      xp[((size_t)b*256 + cg)*PPX + R*32 + 2*j + halfsel] = vmax[j];
  }
}

// ================= qkv 1x1 conv (672 needed rows) =================
__global__ __launch_bounds__(256) void k_qkv(const float* __restrict__ xp, const float* __restrict__ wq,
        const float* __restrict__ bq, float* __restrict__ qkvm) {
  int pt = blockIdx.x, ot = blockIdx.y, b = blockIdx.z;
  int t = threadIdx.x;
  int ol = t & 31, pg = t >> 5;
  __shared__ float wsh[32][9];
  __shared__ float xsh[8][260];
  float acc[32];
  #pragma unroll
  for (int j = 0; j < 32; ++j) acc[j] = 0.0f;
  for (int ic0 = 0; ic0 < 256; ic0 += 8) {
    {
      int o = t >> 3, j = t & 7;
      int orow = ot*32 + o;
      int reg = orow/224, rem = orow - reg*224;
      int wrow = 32 + rem + 256*reg;
      wsh[o][j] = wq[(size_t)wrow*256 + ic0 + j];
    }
    for (int q = t; q < 2048; q += 256) {
      int ic = q >> 8, px = q & 255;
      xsh[ic][px] = xp[((size_t)b*256 + ic0 + ic)*PPX + pt*256 + px];
    }
    __syncthreads();
    for (int ic = 0; ic < 8; ++ic) {
      float a = wsh[ol][ic];
      const float* xr = &xsh[ic][pg];
      #pragma unroll
      for (int j = 0; j < 32; ++j) acc[j] += a*xr[8*j];
    }
    __syncthreads();
  }
  int orow = ot*32 + ol;
  int reg = orow/224, rem = orow - reg*224;
  float bv = bq[32 + rem + 256*reg];
  #pragma unroll
  for (int j = 0; j < 32; ++j)
    qkvm[((size_t)b*672 + orow)*PPX + pt*256 + pg + 8*j] = acc[j] + bv;
}

// ================= attention =================
__global__ __launch_bounds__(256) void k_attn(const float* __restrict__ qkvm, const float* __restrict__ emb,
        const float* __restrict__ xp, float* __restrict__ pool) {
  int rt = blockIdx.x, n = blockIdx.y, b = blockIdx.z;
  int t = threadIdx.x;
  int rl = t >> 5, pg = t & 31;
  __shared__ float S[8][1032];
  __shared__ float qsh[8][33];
  __shared__ float kv[4224];
  const float* qb = qkvm + (size_t)b*672*PPX;
  int rg0 = rt*8;
  {
    int rg = rg0 + rl;
    float qv = qb[(size_t)(32*n + (rg >> 5))*PPX + ((rg & 31) << 5) + pg];
    float ev = emb[(((size_t)n*8 + b)*1024 + rg)*32 + pg];
    qsh[rl][pg] = (qv + ev)*0.17677669529663688f;
  }
  __syncthreads();
  const float* kb = qb + (size_t)(224 + 32*n)*PPX;
  for (int p0 = 0; p0 < 1024; p0 += 128) {
    for (int q = t; q < 4096; q += 256) {
      int c = q >> 7, pp = q & 127;
      kv[c*132 + pp] = kb[(size_t)c*PPX + p0 + pp];
    }
    __syncthreads();
    float a0 = 0, a1 = 0, a2 = 0, a3 = 0;
    for (int c = 0; c < 32; ++c) {
      float qv = qsh[rl][c];
      const float* kr = &kv[c*132 + pg];
      a0 += qv*kr[0]; a1 += qv*kr[32]; a2 += qv*kr[64]; a3 += qv*kr[96];
    }
    S[rl][p0 + pg]      = a0;
    S[rl][p0 + pg + 32] = a1;
    S[rl][p0 + pg + 64] = a2;
    S[rl][p0 + pg + 96] = a3;
    __syncthreads();
  }
  float mx = -3.0e38f;
  for (int j = 0; j < 32; ++j) mx = fmaxf(mx, S[rl][pg + 32*j]);
  #pragma unroll
  for (int m = 1; m <= 16; m <<= 1) mx = fmaxf(mx, __shfl_xor(mx, m));
  float sum = 0.0f;
  for (int j = 0; j < 32; ++j) {
    float e = expf(S[rl][pg + 32*j] - mx);
    S[rl][pg + 32*j] = e;
    sum += e;
  }
  #pragma unroll
  for (int m = 1; m <= 16; m <<= 1) sum += __shfl_xor(sum, m);
  float inv = 1.0f/sum;
  for (int j = 0; j < 32; ++j) S[rl][pg + 32*j] *= inv;
  __syncthreads();
  const float* vb = qb + (size_t)(448 + 32*n)*PPX;
  float acc = 0.0f;
  for (int p0 = 0; p0 < 1024; p0 += 128) {
    for (int q = t; q < 4096; q += 256) {
      int pp = q >> 5, c = q & 31;
      int p = p0 + pp;
      kv[pp*33 + c] = vb[(size_t)(p >> 5)*PPX + ((p & 31) << 5) + c];
    }
    __syncthreads();
    for (int pp = 0; pp < 128; ++pp) acc += S[rl][p0 + pp]*kv[pp*33 + pg];
    __syncthreads();
  }
  int rg = rg0 + rl;
  int ch = 32*n + (rg >> 5);
  size_t sp = (size_t)((rg & 31) << 5) + pg;
  pool[((size_t)b*224 + ch)*PPX + sp] = acc + xp[((size_t)b*256 + 32 + ch)*PPX + sp];
}

__global__ void k_owt(const float* __restrict__ ow, float* __restrict__ owt) {
  int t = blockIdx.x*256 + threadIdx.x;
  if (t < 256*224) {
    int oc = t/224, ch = t - oc*224;
    owt[(size_t)ch*256 + oc] = ow[t];
  }
}

// ================= bilinear + sim gating + final conv =================
__global__ __launch_bounds__(256) void k_final(const float* __restrict__ pool, const float* __restrict__ noise,
        const float* __restrict__ sim_w, const float* __restrict__ owt, float* __restrict__ out) {
  int tt = blockIdx.x, b = blockIdx.y;
  int t = threadIdx.x;
  int h = tt >> 3, w0 = (tt & 7)*16;
  __shared__ float xa[224][20];
  __shared__ float nsc[224][20];
  __shared__ float nz[32][20];
  __shared__ float scl[16];
  for (int q = t; q < 512; q += 256) {
    int c = q >> 4, px = q & 15;
    nz[c][px] = noise[((size_t)b*32 + c)*NPX + h*128 + w0 + px];
  }
  float hs = h*0.25f - 0.375f;
  float hf = floorf(hs);
  int h0 = (int)hf;
  float fh = hs - hf;
  int h0c = min(max(h0, 0), 31);
  int h1c = min(max(h0 + 1, 0), 31);
  __syncthreads();
  for (int q = t; q < 3584; q += 256) {
    int c = q >> 4, px = q & 15;
    int w = w0 + px;
    float wsrc = w*0.25f - 0.375f;
    float wf = floorf(wsrc);
    int W0 = (int)wf;
    float fw = wsrc - wf;
    int w0c = min(max(W0, 0), 31);
    int w1c = min(max(W0 + 1, 0), 31);
    const float* pb = pool + ((size_t)b*224 + c)*PPX;
    float v00 = pb[h0c*32 + w0c], v01 = pb[h0c*32 + w1c];
    float v10 = pb[h1c*32 + w0c], v11 = pb[h1c*32 + w1c];
    xa[c][px] = (1.0f - fh)*((1.0f - fw)*v00 + fw*v01) + fh*((1.0f - fw)*v10 + fw*v11);
    float np = 0.0f;
    #pragma unroll
    for (int j = 0; j < 32; ++j) np += sim_w[c*32 + j]*nz[j][px];
    nsc[c][px] = np;
  }
  __syncthreads();
  {
    int px = t >> 4, kk = t & 15;
    float s1 = 0, s2 = 0, s3 = 0;
    for (int c = kk; c < 224; c += 16) {
      float a = xa[c][px], p = nsc[c][px];
      s1 += a*a; s2 += p*p; s3 += a*p;
    }
    #pragma unroll
    for (int m = 1; m <= 8; m <<= 1) {
      s1 += __shfl_xor(s1, m);
      s2 += __shfl_xor(s2, m);
      s3 += __shfl_xor(s3, m);
    }
    if (kk == 0) {
      float n1 = fmaxf(sqrtf(s1), 1e-12f);
      float n2 = fmaxf(sqrtf(s2), 1e-12f);
      float sim = (s3/(n1*n2) + 1.0f)*0.5f;
      scl[px] = 1.0f - sim;
    }
  }
  __syncthreads();
  {
    float accp[16];
    #pragma unroll
    for (int px = 0; px < 16; ++px) accp[px] = 0.0f;
    for (int c = 0; c < 224; ++c) {
      float wv = owt[(size_t)c*256 + t];
      #pragma unroll
      for (int px = 0; px < 16; ++px) accp[px] += wv*xa[c][px];
    }
    size_t obase = ((size_t)b*256 + t)*NPX + (size_t)h*128 + w0;
    #pragma unroll
    for (int px = 0; px < 16; ++px) out[obase + px] = accp[px]*scl[px];
  }
  if (b == 0 && tt == 0 && t == 0) out[(size_t)33554432] = 8.0f;   // AVG_K
}

extern "C" void kernel_launch(void* const* d_in, const int* in_sizes, int n_in,
                              void* d_out, int out_size, void* d_ws, size_t ws_size,
                              hipStream_t stream) {
  (void)in_sizes; (void)n_in; (void)out_size; (void)ws_size;
  const float* x     = (const float*)d_in[0];
  const float* qkv_w = (const float*)d_in[1];
  const float* qkv_b = (const float*)d_in[2];
  const float* emb   = (const float*)d_in[3];
  const float* sim_w = (const float*)d_in[4];
  const float* out_w = (const float*)d_in[5];
  float* out = (float*)d_out;
  char* ws = (char*)d_ws;
  double* gram = (double*)(ws + OFF_GRAM);
  double* A    = (double*)(ws + OFF_A);
  double* QT   = (double*)(ws + OFF_QT);
  double* SG   = (double*)(ws + OFF_SG);
  double* QNT  = (double*)(ws + OFF_QN);
  double* d_a  = (double*)(ws + OFF_D);
  double* e_a  = (double*)(ws + OFF_E);
  double* tau_a= (double*)(ws + OFF_TAU);
  double* DW   = (double*)(ws + OFF_DW);
  int*    META = (int*)   (ws + OFF_META);
  float*  Vt   = (float*) (ws + OFF_VT);
  float*  xp   = (float*) (ws + OFF_XP);
  float*  qkvm = (float*) (ws + OFF_QKV);
  float*  pool = (float*) (ws + OFF_POOL);
  float*  owt  = (float*) (ws + OFF_OWT);
  float*  noise_out = out + 33554433;

  k_gram   <<<dim3(8,8,8),   256,  0, stream>>>(x, gram);
  k_tridiag<<<dim3(8),       1024, 0, stream>>>(gram, A, d_a, e_a, tau_a);
  k_zeroq  <<<dim3(512),     256,  0, stream>>>(QT);
  k_leaves <<<dim3(8),       64,   0, stream>>>(d_a, e_a, QT, DW);
  // merge levels: n1 = 16, 32, 64, 128; nmrg = 8, 4, 2, 1
  {
    const int n1s[4]   = {16, 32, 64, 128};
    const int nmrgs[4] = {8, 4, 2, 1};
    for (int lv = 0; lv < 4; ++lv) {
      int n1 = n1s[lv], nmrg = nmrgs[lv], nn = 2*n1;
      k_mscan<<<dim3(nmrg, 8), 256, 0, stream>>>(n1, e_a, QT, DW, SG, META);
      k_mgemm<<<dim3(nn/32, (nn + 63)/64, nmrg*8), 256, 0, stream>>>(n1, nmrg, QT, SG, META, QNT);
      k_mperm<<<dim3(nmrg, 8), 256, 0, stream>>>(n1, QNT, META, QT);
    }
  }
  k_backxf <<<dim3(16,8),    256, 0, stream>>>(A, tau_a, QT, Vt);
  k_xproj  <<<dim3(32,8,8),  256, 0, stream>>>(x, Vt, xp, noise_out);
  k_qkv    <<<dim3(4,21,8),  256, 0, stream>>>(xp, qkv_w, qkv_b, qkvm);
  k_attn   <<<dim3(128,7,8), 256, 0, stream>>>(qkvm, emb, xp, pool);
  k_owt    <<<dim3(224),     256, 0, stream>>>(out_w, owt);
  k_final  <<<dim3(1024,8),  256, 0, stream>>>(pool, noise_out, sim_w, owt, out);
}